// Round 9
// baseline (1446.002 us; speedup 1.0000x reference)
//
#include <hip/hip_runtime.h>
#include <cfloat>
#include <cstdint>
#include <cstddef>

#define NROWS 8192
#define HID 256
#define NCLS 5
#define TOPK 10
#define CAP 256     // per-row candidate capacity (typ. ~20-60 used)
#define TM 128
#define TN 128
#define BK 32

typedef __bf16 bf16x8 __attribute__((ext_vector_type(8)));
typedef float f32x4 __attribute__((ext_vector_type(4)));

__device__ inline ushort f2bf(float x) {
  unsigned u = __float_as_uint(x);
  unsigned r = (u + 0x7fffu + ((u >> 16) & 1u)) >> 16;  // RNE
  return (ushort)r;
}
__device__ inline float bf2f(ushort b) { return __uint_as_float(((unsigned)b) << 16); }

// async global->LDS 16B/lane; LDS dest is wave-uniform base + lane*16
__device__ __forceinline__ void load_lds16(const void* g, void* l) {
  __builtin_amdgcn_global_load_lds(
      (const __attribute__((address_space(1))) void*)g,
      (__attribute__((address_space(3))) void*)l, 16, 0, 0);
}

// ---------------------------------------------------------------------------
// Encoder pack: X rows (M x D fp32 -> hi/lo bf16 limb planes, K padded to Kp)
// and W (D x HID fp32, transposed -> HID x Kp limb planes).
// ---------------------------------------------------------------------------
__global__ __launch_bounds__(256) void packAB_kernel(const float* __restrict__ X,
    const float* __restrict__ W, ushort* __restrict__ Ah, ushort* __restrict__ Al,
    ushort* __restrict__ Bh, ushort* __restrict__ Bl, int D, int Kp, int ksh) {
  const int id = blockIdx.x * 256 + threadIdx.x;
  const int atotal = NROWS << ksh;
  if (id < atotal) {
    const int r = id >> ksh, k = id & (Kp - 1);
    const float x = (k < D) ? X[(size_t)r * D + k] : 0.f;
    const ushort h = f2bf(x);
    Ah[id] = h;
    Al[id] = f2bf(x - bf2f(h));
  } else {
    const int id2 = id - atotal;
    if (id2 < (HID << ksh)) {
      const int n = id2 >> ksh, k = id2 & (Kp - 1);
      const float x = (k < D) ? W[(size_t)k * HID + n] : 0.f;
      const ushort h = f2bf(x);
      Bh[id2] = h;
      Bl[id2] = f2bf(x - bf2f(h));
    }
  }
}

// ---------------------------------------------------------------------------
// GCN weight pack: W [HID x HID] -> transposed limb planes [HID x 256].
// ---------------------------------------------------------------------------
__global__ __launch_bounds__(256) void packW_kernel(const float* __restrict__ W,
    ushort* __restrict__ Bh, ushort* __restrict__ Bl) {
  const int id = blockIdx.x * 256 + threadIdx.x;  // 65536
  const int k = id >> 8, n = id & 255;            // coalesced read over n
  const float x = W[(size_t)k * HID + n];
  const ushort h = f2bf(x);
  Bh[(size_t)n * HID + k] = h;
  Bl[(size_t)n * HID + k] = f2bf(x - bf2f(h));
}

// ---------------------------------------------------------------------------
// 3-segment two-limb bf16 MFMA GEMM: C[NROWS x HID] = act(A @ B^T + bias).
// Segments hh + hl + lh (ll ~2^-18, dropped). 64x64 tile, 4 waves (2x2),
// XCD-swizzled 1-D grid for A-tile L2 reuse.
// ---------------------------------------------------------------------------
template<bool BIAS, int ACT>
__global__ __launch_bounds__(256) void limbgemm_kernel(const ushort* __restrict__ Ah,
    const ushort* __restrict__ Al, const ushort* __restrict__ Bh,
    const ushort* __restrict__ Bl, const float* __restrict__ bias,
    float* __restrict__ C, int Kp) {
  __shared__ ushort AsH[64 * BK], AsL[64 * BK], BsH[64 * BK], BsL[64 * BK];
  const int tid = threadIdx.x;
  const int wave = tid >> 6, lane = tid & 63;
  const int bid = blockIdx.x;
  const int xcd = bid & 7, slot = bid >> 3;
  const int bxi = slot & 3;
  const int byi = xcd * 16 + (slot >> 2);
  const int bm = byi * 64, bn = bxi * 64;
  const int wr = (wave >> 1) * 32, wc = (wave & 1) * 32;

  f32x4 acc[2][2];
  const f32x4 zero = {0.f, 0.f, 0.f, 0.f};
  acc[0][0] = zero; acc[0][1] = zero; acc[1][0] = zero; acc[1][1] = zero;

  const int r0 = tid >> 2, kl0 = (tid & 3) ^ ((r0 & 3) ^ ((r0 >> 2) & 1));
  const size_t aoff = (size_t)(bm + r0) * Kp + kl0 * 8;
  const size_t boff = (size_t)(bn + r0) * Kp + kl0 * 8;

  for (int k0 = 0; k0 < Kp; k0 += BK) {
    __syncthreads();
    load_lds16(Ah + aoff + k0, &AsH[tid * 8]);
    load_lds16(Al + aoff + k0, &AsL[tid * 8]);
    load_lds16(Bh + boff + k0, &BsH[tid * 8]);
    load_lds16(Bl + boff + k0, &BsL[tid * 8]);
    __syncthreads();
    bf16x8 ah[2], al[2], bh[2], bl[2];
    const int kg = lane >> 4;
    #pragma unroll
    for (int f = 0; f < 2; ++f) {
      const int m = wr + f * 16 + (lane & 15);
      const int sa = m * 4 + (kg ^ (m & 3) ^ ((m >> 2) & 1));
      ah[f] = *(const bf16x8*)&AsH[sa * 8];
      al[f] = *(const bf16x8*)&AsL[sa * 8];
      const int n = wc + f * 16 + (lane & 15);
      const int sb = n * 4 + (kg ^ (n & 3) ^ ((n >> 2) & 1));
      bh[f] = *(const bf16x8*)&BsH[sb * 8];
      bl[f] = *(const bf16x8*)&BsL[sb * 8];
    }
    #pragma unroll
    for (int fr = 0; fr < 2; ++fr)
      #pragma unroll
      for (int fc = 0; fc < 2; ++fc) {
        acc[fr][fc] = __builtin_amdgcn_mfma_f32_16x16x32_bf16(ah[fr], bh[fc], acc[fr][fc], 0, 0, 0);
        acc[fr][fc] = __builtin_amdgcn_mfma_f32_16x16x32_bf16(ah[fr], bl[fc], acc[fr][fc], 0, 0, 0);
        acc[fr][fc] = __builtin_amdgcn_mfma_f32_16x16x32_bf16(al[fr], bh[fc], acc[fr][fc], 0, 0, 0);
      }
  }
  const int cq = lane >> 4, cc = lane & 15;
  #pragma unroll
  for (int fr = 0; fr < 2; ++fr) {
    #pragma unroll
    for (int fc = 0; fc < 2; ++fc) {
      const int rb = bm + wr + fr * 16 + cq * 4;
      const int col = bn + wc + fc * 16 + cc;
      const float bb = BIAS ? bias[col] : 0.f;
      float* cp = C + (size_t)rb * HID + col;
      #pragma unroll
      for (int e = 0; e < 4; ++e) {
        float v = acc[fr][fc][e] + bb;
        if (ACT == 1) v = fmaxf(v, 0.f);
        cp[(size_t)e * HID] = v;
      }
    }
  }
}

// ---------------------------------------------------------------------------
// Coalesced BatchNorm, 3 stages.
// ---------------------------------------------------------------------------
__global__ __launch_bounds__(256) void bn_stats_kernel(const float* __restrict__ F,
    float* __restrict__ ps, float* __restrict__ ps2) {
  const int b = blockIdx.x, t = threadIdx.x;
  float s = 0.f, s2 = 0.f;
  const float* p = F + (size_t)b * 128 * HID + t;
  for (int r = 0; r < 128; ++r) {
    const float v = p[(size_t)r * HID];
    s += v; s2 += v * v;
  }
  ps[b * HID + t] = s;
  ps2[b * HID + t] = s2;
}

__global__ __launch_bounds__(256) void bn_finalize_kernel(const float* __restrict__ ps,
    const float* __restrict__ ps2, const float* __restrict__ g,
    const float* __restrict__ b, float* __restrict__ scale, float* __restrict__ shift) {
  const int t = threadIdx.x;
  float s = 0.f, s2 = 0.f;
  for (int i = 0; i < 64; ++i) { s += ps[i * HID + t]; s2 += ps2[i * HID + t]; }
  const float mu = s / (float)NROWS;
  const float var = s2 / (float)NROWS - mu * mu;
  const float rstd = rsqrtf(var + 1e-5f);
  const float sc = rstd * g[t];
  scale[t] = sc;
  shift[t] = b[t] - mu * sc;
}

// ---------------------------------------------------------------------------
// Fused bn-apply + L2 rownorm. Emits FN (fp32 fn), Ph (hi-limb fn),
// Fh/Fl (two-limb bn'd feat for gc1).
// ---------------------------------------------------------------------------
__global__ __launch_bounds__(256) void bn_rownorm_kernel(const float* __restrict__ F,
    const float* __restrict__ scale, const float* __restrict__ shift,
    float* __restrict__ FN, ushort* __restrict__ Ph,
    ushort* __restrict__ Fh, ushort* __restrict__ Fl) {
  const int r = blockIdx.x, t = threadIdx.x;
  const float f = F[(size_t)r * HID + t] * scale[t] + shift[t];
  __shared__ float sh[256];
  sh[t] = f * f;
  __syncthreads();
  for (int st = 128; st > 0; st >>= 1) {
    if (t < st) sh[t] += sh[t + st];
    __syncthreads();
  }
  const float inv = 1.0f / fmaxf(sqrtf(sh[0]), 1e-12f);
  const float fn = f * inv;
  const size_t o = (size_t)r * HID + t;
  FN[o] = fn;
  Ph[o] = f2bf(fn);
  const ushort h = f2bf(f);
  Fh[o] = h;
  Fl[o] = f2bf(f - bf2f(h));
}

// ---------------------------------------------------------------------------
// Stripe-free sim: 128x128 tiles of Ph @ Ph^T (K=256 hi-limb MFMA).
// FULL-K LDS staging: both 128x256 bf16 tiles (64+64 KB) loaded with one
// async burst + ONE barrier, then 128 MFMA/wave uninterrupted (the R8
// version paid 16 barrier drains for the same work).
// PASS 0: epilogue reduces tile to per-row tile-max (self-excluded) -> M.
// PASS 1: recompute tile; lanes append register values >= tau[row] to the
//         per-row global candidate list (device atomics; ~30 hits/row total).
// Sim values never touch HBM.
// ---------------------------------------------------------------------------
template<int PASS>
__global__ __launch_bounds__(256) void simtile_kernel(const ushort* __restrict__ P,
    float* __restrict__ M, const float* __restrict__ tauv,
    int* __restrict__ gcnt, int* __restrict__ gidx) {
  __shared__ ushort As[TM * HID];   // 64 KB
  __shared__ ushort Bs[TN * HID];   // 64 KB
  __shared__ float Ml[2][TM];
  __shared__ float taul[TM];
  const int tid = threadIdx.x;
  const int wave = tid >> 6, lane = tid & 63;
  const int bm = blockIdx.y * TM;
  const int bn = blockIdx.x * TN;
  const int wr = (wave >> 1) * 64;
  const int wc = (wave & 1) * 64;

  if (PASS == 1 && tid < TM) taul[tid] = tauv[bm + tid];

  const int p0 = tid, p1 = tid + 256;
  const int r0 = p0 >> 2, kl0 = (p0 & 3) ^ ((r0 & 3) ^ ((r0 >> 2) & 1));
  const int r1 = p1 >> 2, kl1 = (p1 & 3) ^ ((r1 & 3) ^ ((r1 >> 2) & 1));
  const ushort* pa0 = P + (size_t)(bm + r0) * HID + kl0 * 8;
  const ushort* pa1 = P + (size_t)(bm + r1) * HID + kl1 * 8;
  const ushort* pb0 = P + (size_t)(bn + r0) * HID + kl0 * 8;
  const ushort* pb1 = P + (size_t)(bn + r1) * HID + kl1 * 8;

  // stage the full K=256 for both tiles, then one barrier
  #pragma unroll
  for (int c = 0; c < 8; ++c) {
    load_lds16(pa0 + c * 32, &As[c * 4096 + p0 * 8]);
    load_lds16(pa1 + c * 32, &As[c * 4096 + p1 * 8]);
    load_lds16(pb0 + c * 32, &Bs[c * 4096 + p0 * 8]);
    load_lds16(pb1 + c * 32, &Bs[c * 4096 + p1 * 8]);
  }
  __syncthreads();

  f32x4 acc[4][4];
  const f32x4 zero = {0.f, 0.f, 0.f, 0.f};
  #pragma unroll
  for (int i = 0; i < 4; ++i)
    #pragma unroll
    for (int j = 0; j < 4; ++j) acc[i][j] = zero;

  const int kg = lane >> 4;
  #pragma unroll
  for (int c = 0; c < 8; ++c) {
    bf16x8 af[4], bf[4];
    #pragma unroll
    for (int f = 0; f < 4; ++f) {
      const int m = wr + f * 16 + (lane & 15);
      const int sa = m * 4 + (kg ^ (m & 3) ^ ((m >> 2) & 1));
      af[f] = *(const bf16x8*)&As[c * 4096 + sa * 8];
      const int n = wc + f * 16 + (lane & 15);
      const int sb = n * 4 + (kg ^ (n & 3) ^ ((n >> 2) & 1));
      bf[f] = *(const bf16x8*)&Bs[c * 4096 + sb * 8];
    }
    #pragma unroll
    for (int fr = 0; fr < 4; ++fr)
      #pragma unroll
      for (int fc = 0; fc < 4; ++fc)
        acc[fr][fc] = __builtin_amdgcn_mfma_f32_16x16x32_bf16(af[fr], bf[fc], acc[fr][fc], 0, 0, 0);
  }

  const int cq = lane >> 4, cc = lane & 15;
  if (PASS == 0) {
    #pragma unroll
    for (int fr = 0; fr < 4; ++fr) {
      #pragma unroll
      for (int e = 0; e < 4; ++e) {
        const int lrow = wr + fr * 16 + cq * 4 + e;
        const int grow = bm + lrow;
        float mx = -FLT_MAX;
        #pragma unroll
        for (int fc = 0; fc < 4; ++fc) {
          const int col = bn + wc + fc * 16 + cc;
          mx = fmaxf(mx, (col == grow) ? -FLT_MAX : acc[fr][fc][e]);
        }
        #pragma unroll
        for (int s = 1; s < 16; s <<= 1) mx = fmaxf(mx, __shfl_xor(mx, s));
        if (cc == 0) Ml[wave & 1][lrow] = mx;
      }
    }
    __syncthreads();
    if (tid < TM) M[(size_t)(bm + tid) * 64 + blockIdx.x] = fmaxf(Ml[0][tid], Ml[1][tid]);
  } else {
    #pragma unroll
    for (int fr = 0; fr < 4; ++fr) {
      #pragma unroll
      for (int e = 0; e < 4; ++e) {
        const int lrow = wr + fr * 16 + cq * 4 + e;
        const int grow = bm + lrow;
        const float t = taul[lrow];
        #pragma unroll
        for (int fc = 0; fc < 4; ++fc) {
          const int col = bn + wc + fc * 16 + cc;
          const float v = acc[fr][fc][e];
          if (col != grow && v >= t) {
            const int pos = atomicAdd(&gcnt[grow], 1);
            if (pos < CAP) gidx[(size_t)grow * CAP + pos] = col;
          }
        }
      }
    }
  }
}

// ---------------------------------------------------------------------------
// tau[row] = 16th largest of the 64 tile-maxes (valid top-16 lower bound:
// the top-16 tiles' maxes are 16 distinct non-self elements >= tau).
// Also zeroes gcnt (ws is re-poisoned before every launch).
// ---------------------------------------------------------------------------
__global__ __launch_bounds__(256) void tau_kernel(const float* __restrict__ M,
    float* __restrict__ tauv, int* __restrict__ gcnt) {
  const int wave = threadIdx.x >> 6, lane = threadIdx.x & 63;
  const int row = blockIdx.x * 4 + wave;
  float cur = M[(size_t)row * 64 + lane];
  float tau = cur;
  #pragma unroll
  for (int sel = 0; sel < 16; ++sel) {
    float bv = cur;
    int bl = lane;
    #pragma unroll
    for (int s = 1; s < 64; s <<= 1) {
      const float ov = __shfl_xor(bv, s);
      const int ol = __shfl_xor(bl, s);
      if (ov > bv || (ov == bv && ol < bl)) { bv = ov; bl = ol; }
    }
    tau = bv;
    if (lane == bl) cur = -FLT_MAX;
  }
  if (lane == 0) { tauv[row] = tau; gcnt[row] = 0; }
}

// ---------------------------------------------------------------------------
// Exact refinement: fp32 dots for all candidates, exact top-10, L1-normalize.
// One wave per row.
// ---------------------------------------------------------------------------
__global__ __launch_bounds__(256) void refine_kernel(const int* __restrict__ gcnt,
    const int* __restrict__ gidx, const float* __restrict__ FN,
    int* __restrict__ nidx, float* __restrict__ nval, float* __restrict__ dinv) {
  const int wave = threadIdx.x >> 6, lane = threadIdx.x & 63;
  const int row = blockIdx.x * 4 + wave;
  const int cnt = min(gcnt[row], CAP);
  __shared__ float fnrow[4][HID];
  __shared__ float ev[4][CAP];
  ((float4*)fnrow[wave])[lane] = ((const float4*)(FN + (size_t)row * HID))[lane];
  __syncthreads();
  const int c = lane >> 2, q4 = lane & 3;
  for (int b0 = 0; b0 < cnt; b0 += 16) {
    const int ci = b0 + c;
    const int cand = (ci < cnt) ? gidx[(size_t)row * CAP + ci] : 0;
    float s = 0.f;
    const float* fc = FN + (size_t)cand * HID + q4 * 64;
    const float* fr = fnrow[wave] + q4 * 64;
    #pragma unroll 8
    for (int k = 0; k < 64; ++k) s += fr[k] * fc[k];
    s += __shfl_xor(s, 1);
    s += __shfl_xor(s, 2);
    if (q4 == 0 && ci < cnt) ev[wave][ci] = s;
  }
  __syncthreads();
  float outv[TOPK];
  int outi[TOPK];
  float sum = 1.0f;  // diag contributes 1
  #pragma unroll
  for (int sel = 0; sel < TOPK; ++sel) {
    float bv = -FLT_MAX;
    int bp = 0;
    #pragma unroll
    for (int j = 0; j < 4; ++j) {
      const int p = lane + j * 64;
      if (p < cnt) {
        const float v = ev[wave][p];
        if (v > bv) { bv = v; bp = p; }
      }
    }
    #pragma unroll
    for (int s = 1; s < 64; s <<= 1) {
      const float ov = __shfl_xor(bv, s);
      const int op = __shfl_xor(bp, s);
      if (ov > bv || (ov == bv && op < bp)) { bv = ov; bp = op; }
    }
    outv[sel] = bv;
    outi[sel] = bp;
    sum += fabsf(bv);
    if (lane == 0) ev[wave][bp] = -FLT_MAX;
  }
  if (lane == 0) {
    const float inv = 1.0f / fmaxf(sum, 1e-12f);
    dinv[row] = inv;
    #pragma unroll
    for (int sel = 0; sel < TOPK; ++sel) {
      nval[row * TOPK + sel] = outv[sel] * inv;
      nidx[row * TOPK + sel] = gidx[(size_t)row * CAP + outi[sel]];
    }
  }
}

// ---------------------------------------------------------------------------
// Sparse adj (11 nnz/row) @ T + bias, leaky_relu(0.25).
// EMIT=0: write fp32 H. EMIT=1: write two-limb bf16 planes (next gemm's A).
// ---------------------------------------------------------------------------
template<int EMIT>
__global__ __launch_bounds__(256) void spmm_kernel(const float* __restrict__ T,
    const int* __restrict__ nidx, const float* __restrict__ nval,
    const float* __restrict__ dinv, const float* __restrict__ bias,
    float* __restrict__ H, ushort* __restrict__ Hh, ushort* __restrict__ Hl) {
  const int r = blockIdx.x, c = threadIdx.x;
  float acc = dinv[r] * T[(size_t)r * HID + c];
  #pragma unroll
  for (int n = 0; n < TOPK; ++n) {
    acc += nval[r * TOPK + n] * T[(size_t)nidx[r * TOPK + n] * HID + c];
  }
  acc += bias[c];
  const float v = acc >= 0.f ? acc : 0.25f * acc;
  const size_t o = (size_t)r * HID + c;
  if (EMIT == 0) {
    H[o] = v;
  } else {
    const ushort h = f2bf(v);
    Hh[o] = h;
    Hl[o] = f2bf(v - bf2f(h));
  }
}

__global__ __launch_bounds__(256) void clf_kernel(const float* __restrict__ H,
    const float* __restrict__ W, const float* __restrict__ b,
    float* __restrict__ L) {
  const int id = blockIdx.x * 256 + threadIdx.x;
  if (id >= NROWS * NCLS) return;
  const int r = id / NCLS, c = id % NCLS;
  float s = b[c];
  const float* hr = H + (size_t)r * HID;
  for (int k = 0; k < HID; ++k) s += hr[k] * W[k * NCLS + c];
  L[id] = s;
}

__global__ __launch_bounds__(256) void fuse_kernel(const float* __restrict__ L,
    const float* __restrict__ attn, float* __restrict__ fused) {
  const int id = blockIdx.x * 256 + threadIdx.x;
  if (id >= NROWS * NCLS) return;
  const float a0 = attn[0], a1 = attn[1], a2 = attn[2];
  const float m = fmaxf(a0, fmaxf(a1, a2));
  const float e0 = expf(a0 - m), e1 = expf(a1 - m), e2 = expf(a2 - m);
  const float inv = 1.0f / (e0 + e1 + e2);
  const float l0 = L[id];
  const float l1 = L[NROWS * NCLS + id];
  const float l2 = L[2 * NROWS * NCLS + id];
  const float s0 = 1.0f / (1.0f + expf(-l0));
  const float s1 = 1.0f / (1.0f + expf(-l1));
  const float s2 = 1.0f / (1.0f + expf(-l2));
  fused[id] = (e0 * s0 + e1 * s1 + e2 * s2) * inv;
}

__global__ __launch_bounds__(128) void head_kernel(const float* __restrict__ fused,
    const float* __restrict__ W1, const float* __restrict__ b1,
    const float* __restrict__ W2, const float* __restrict__ b2,
    float* __restrict__ out) {
  const int r = blockIdx.x, t = threadIdx.x;
  __shared__ float f[NCLS];
  __shared__ float hh[128];
  if (t < NCLS) f[t] = fused[r * NCLS + t];
  __syncthreads();
  float s = b1[t];
  #pragma unroll
  for (int k = 0; k < NCLS; ++k) s += f[k] * W1[k * 128 + t];
  hh[t] = s >= 0.f ? s : 0.25f * s;
  __syncthreads();
  if (t < NCLS) {
    float o = b2[t];
    for (int k = 0; k < 128; ++k) o += hh[k] * W2[k * NCLS + t];
    out[r * NCLS + t] = o;
  }
}

// ---------------------------------------------------------------------------
extern "C" void kernel_launch(void* const* d_in, const int* in_sizes, int n_in,
                              void* d_out, int out_size, void* d_ws, size_t ws_size,
                              hipStream_t stream) {
  const float* x[3]    = {(const float*)d_in[0], (const float*)d_in[1], (const float*)d_in[2]};
  const float* encW[3] = {(const float*)d_in[3], (const float*)d_in[4], (const float*)d_in[5]};
  const float* enc_b = (const float*)d_in[6];
  const float* bn_g  = (const float*)d_in[7];
  const float* bn_b  = (const float*)d_in[8];
  const float* gc1W  = (const float*)d_in[9];
  const float* gc1b  = (const float*)d_in[10];
  const float* gc2W  = (const float*)d_in[11];
  const float* gc2b  = (const float*)d_in[12];
  const float* clfW  = (const float*)d_in[13];
  const float* clfb  = (const float*)d_in[14];
  const float* attn  = (const float*)d_in[15];
  const float* f1W   = (const float*)d_in[16];
  const float* f1b   = (const float*)d_in[17];
  const float* f2W   = (const float*)d_in[18];
  const float* f2b   = (const float*)d_in[19];
  float* out = (float*)d_out;

  // Workspace layout
  const size_t NH = (size_t)NROWS * HID;
  float* ws = (float*)d_ws;
  float* FN = ws;                                  // fp32 fn
  float* A  = FN + NH;                             // encoder out (pre-bn)
  float* C  = A + NH;                              // gemm temp
  float* Bf = C + NH;                              // h2 fp32
  int*   nidx = (int*)(Bf + NH);
  float* nval = (float*)(nidx + (size_t)NROWS * TOPK);
  float* dinv = nval + (size_t)NROWS * TOPK;
  float* logits = dinv + NROWS;
  float* fused = logits + (size_t)3 * NROWS * NCLS;
  float* ps    = fused + (size_t)NROWS * NCLS;     // 64*256
  float* ps2   = ps + 64 * HID;
  float* scale = ps2 + 64 * HID;
  float* shift = scale + HID;
  float* M     = shift + HID;                      // 8192*64 tile maxes
  float* tauv  = M + (size_t)NROWS * 64;           // 8192
  int*   gcnt  = (int*)(tauv + NROWS);             // 8192
  int*   gidx  = gcnt + NROWS;                     // 8192*CAP
  ushort* Ph = (ushort*)(gidx + (size_t)NROWS * CAP);  // hi-limb fn
  ushort* Fh = Ph + NH;                            // gc1 A limbs
  ushort* Fl = Fh + NH;
  ushort* Hh = Fl + NH;                            // gc2 A limbs
  ushort* Hl = Hh + NH;
  ushort* Ah = Hl + NH;                            // encoder A limbs (Kp<=1024)
  ushort* Al = Ah + (size_t)NROWS * 1024;
  ushort* Wh = Al + (size_t)NROWS * 1024;          // B limbs (HID x Kp<=1024)
  ushort* Wl = Wh + (size_t)HID * 1024;

  const dim3 blk(256);
  for (int i = 0; i < 3; ++i) {
    const int D = in_sizes[i] / NROWS;
    int Kp = 256, ksh = 8;
    while (Kp < D) { Kp <<= 1; ksh++; }
    // encoder: pack limbs of x and W^T, then A = relu(x @ W + b)
    packAB_kernel<<<((NROWS + HID) << ksh) / 256, blk, 0, stream>>>(
        x[i], encW[i], Ah, Al, Wh, Wl, D, Kp, ksh);
    limbgemm_kernel<true, 1><<<512, blk, 0, stream>>>(Ah, Al, Wh, Wl,
                                                      enc_b + i * HID, A, Kp);
    // coalesced BN + fused rownorm/limb-emit
    bn_stats_kernel<<<64, blk, 0, stream>>>(A, ps, ps2);
    bn_finalize_kernel<<<1, blk, 0, stream>>>(ps, ps2, bn_g + i * HID, bn_b + i * HID,
                                              scale, shift);
    bn_rownorm_kernel<<<NROWS, blk, 0, stream>>>(A, scale, shift, FN, Ph, Fh, Fl);
    // stripe-free knn graph: tile-max pass -> tau -> compaction pass -> refine
    simtile_kernel<0><<<dim3(64, 64), blk, 0, stream>>>(Ph, M, nullptr, nullptr, nullptr);
    tau_kernel<<<NROWS / 4, blk, 0, stream>>>(M, tauv, gcnt);
    simtile_kernel<1><<<dim3(64, 64), blk, 0, stream>>>(Ph, nullptr, tauv, gcnt, gidx);
    refine_kernel<<<NROWS / 4, blk, 0, stream>>>(gcnt, gidx, FN, nidx, nval, dinv);
    // gc1: C = feat @ W1 (limb MFMA), h1 -> limbs via spmm epilogue
    packW_kernel<<<(HID * HID) / 256, blk, 0, stream>>>(gc1W + (size_t)i * HID * HID, Wh, Wl);
    limbgemm_kernel<false, 0><<<512, blk, 0, stream>>>(Fh, Fl, Wh, Wl, nullptr, C, HID);
    spmm_kernel<1><<<NROWS, blk, 0, stream>>>(C, nidx, nval, dinv, gc1b + i * HID,
                                              nullptr, Hh, Hl);
    // gc2
    packW_kernel<<<(HID * HID) / 256, blk, 0, stream>>>(gc2W + (size_t)i * HID * HID, Wh, Wl);
    limbgemm_kernel<false, 0><<<512, blk, 0, stream>>>(Hh, Hl, Wh, Wl, nullptr, C, HID);
    spmm_kernel<0><<<NROWS, blk, 0, stream>>>(C, nidx, nval, dinv, gc2b + i * HID,
                                              Bf, nullptr, nullptr);
    clf_kernel<<<(NROWS * NCLS + 255) / 256, blk, 0, stream>>>(Bf, clfW + (size_t)i * HID * NCLS,
                                                               clfb + i * NCLS,
                                                               logits + (size_t)i * NROWS * NCLS);
  }
  fuse_kernel<<<(NROWS * NCLS + 255) / 256, blk, 0, stream>>>(logits, attn, fused);
  head_kernel<<<NROWS, dim3(128), 0, stream>>>(fused, f1W, f1b, f2W, f2b, out);
}

// Round 10
// 1074.748 us; speedup vs baseline: 1.3454x; 1.3454x over previous
//
#include <hip/hip_runtime.h>
#include <cfloat>
#include <cstdint>
#include <cstddef>

#define NROWS 8192
#define HID 256
#define NCLS 5
#define TOPK 10
#define CAP 256     // per-row candidate capacity (typ. ~20-60 used)
#define TM 128
#define TN 128
#define BK 32
#define BKS 64      // sim K-step (2x MFMA per barrier vs R8)

typedef __bf16 bf16x8 __attribute__((ext_vector_type(8)));
typedef float f32x4 __attribute__((ext_vector_type(4)));

__device__ inline ushort f2bf(float x) {
  unsigned u = __float_as_uint(x);
  unsigned r = (u + 0x7fffu + ((u >> 16) & 1u)) >> 16;  // RNE
  return (ushort)r;
}
__device__ inline float bf2f(ushort b) { return __uint_as_float(((unsigned)b) << 16); }

// async global->LDS 16B/lane; LDS dest is wave-uniform base + lane*16
__device__ __forceinline__ void load_lds16(const void* g, void* l) {
  __builtin_amdgcn_global_load_lds(
      (const __attribute__((address_space(1))) void*)g,
      (__attribute__((address_space(3))) void*)l, 16, 0, 0);
}

// ---------------------------------------------------------------------------
// Encoder pack: X rows (M x D fp32 -> hi/lo bf16 limb planes, K padded to Kp)
// and W (D x HID fp32, transposed -> HID x Kp limb planes).
// ---------------------------------------------------------------------------
__global__ __launch_bounds__(256) void packAB_kernel(const float* __restrict__ X,
    const float* __restrict__ W, ushort* __restrict__ Ah, ushort* __restrict__ Al,
    ushort* __restrict__ Bh, ushort* __restrict__ Bl, int D, int Kp, int ksh) {
  const int id = blockIdx.x * 256 + threadIdx.x;
  const int atotal = NROWS << ksh;
  if (id < atotal) {
    const int r = id >> ksh, k = id & (Kp - 1);
    const float x = (k < D) ? X[(size_t)r * D + k] : 0.f;
    const ushort h = f2bf(x);
    Ah[id] = h;
    Al[id] = f2bf(x - bf2f(h));
  } else {
    const int id2 = id - atotal;
    if (id2 < (HID << ksh)) {
      const int n = id2 >> ksh, k = id2 & (Kp - 1);
      const float x = (k < D) ? W[(size_t)k * HID + n] : 0.f;
      const ushort h = f2bf(x);
      Bh[id2] = h;
      Bl[id2] = f2bf(x - bf2f(h));
    }
  }
}

// ---------------------------------------------------------------------------
// GCN weight pack: W [HID x HID] -> transposed limb planes [HID x 256].
// ---------------------------------------------------------------------------
__global__ __launch_bounds__(256) void packW_kernel(const float* __restrict__ W,
    ushort* __restrict__ Bh, ushort* __restrict__ Bl) {
  const int id = blockIdx.x * 256 + threadIdx.x;  // 65536
  const int k = id >> 8, n = id & 255;            // coalesced read over n
  const float x = W[(size_t)k * HID + n];
  const ushort h = f2bf(x);
  Bh[(size_t)n * HID + k] = h;
  Bl[(size_t)n * HID + k] = f2bf(x - bf2f(h));
}

// ---------------------------------------------------------------------------
// 3-segment two-limb bf16 MFMA GEMM: C[NROWS x HID] = act(A @ B^T + bias).
// Segments hh + hl + lh (ll ~2^-18, dropped). 64x64 tile, 4 waves (2x2),
// XCD-swizzled 1-D grid for A-tile L2 reuse.
// ---------------------------------------------------------------------------
template<bool BIAS, int ACT>
__global__ __launch_bounds__(256) void limbgemm_kernel(const ushort* __restrict__ Ah,
    const ushort* __restrict__ Al, const ushort* __restrict__ Bh,
    const ushort* __restrict__ Bl, const float* __restrict__ bias,
    float* __restrict__ C, int Kp) {
  __shared__ ushort AsH[64 * BK], AsL[64 * BK], BsH[64 * BK], BsL[64 * BK];
  const int tid = threadIdx.x;
  const int wave = tid >> 6, lane = tid & 63;
  const int bid = blockIdx.x;
  const int xcd = bid & 7, slot = bid >> 3;
  const int bxi = slot & 3;
  const int byi = xcd * 16 + (slot >> 2);
  const int bm = byi * 64, bn = bxi * 64;
  const int wr = (wave >> 1) * 32, wc = (wave & 1) * 32;

  f32x4 acc[2][2];
  const f32x4 zero = {0.f, 0.f, 0.f, 0.f};
  acc[0][0] = zero; acc[0][1] = zero; acc[1][0] = zero; acc[1][1] = zero;

  const int r0 = tid >> 2, kl0 = (tid & 3) ^ ((r0 & 3) ^ ((r0 >> 2) & 1));
  const size_t aoff = (size_t)(bm + r0) * Kp + kl0 * 8;
  const size_t boff = (size_t)(bn + r0) * Kp + kl0 * 8;

  for (int k0 = 0; k0 < Kp; k0 += BK) {
    __syncthreads();
    load_lds16(Ah + aoff + k0, &AsH[tid * 8]);
    load_lds16(Al + aoff + k0, &AsL[tid * 8]);
    load_lds16(Bh + boff + k0, &BsH[tid * 8]);
    load_lds16(Bl + boff + k0, &BsL[tid * 8]);
    __syncthreads();
    bf16x8 ah[2], al[2], bh[2], bl[2];
    const int kg = lane >> 4;
    #pragma unroll
    for (int f = 0; f < 2; ++f) {
      const int m = wr + f * 16 + (lane & 15);
      const int sa = m * 4 + (kg ^ (m & 3) ^ ((m >> 2) & 1));
      ah[f] = *(const bf16x8*)&AsH[sa * 8];
      al[f] = *(const bf16x8*)&AsL[sa * 8];
      const int n = wc + f * 16 + (lane & 15);
      const int sb = n * 4 + (kg ^ (n & 3) ^ ((n >> 2) & 1));
      bh[f] = *(const bf16x8*)&BsH[sb * 8];
      bl[f] = *(const bf16x8*)&BsL[sb * 8];
    }
    #pragma unroll
    for (int fr = 0; fr < 2; ++fr)
      #pragma unroll
      for (int fc = 0; fc < 2; ++fc) {
        acc[fr][fc] = __builtin_amdgcn_mfma_f32_16x16x32_bf16(ah[fr], bh[fc], acc[fr][fc], 0, 0, 0);
        acc[fr][fc] = __builtin_amdgcn_mfma_f32_16x16x32_bf16(ah[fr], bl[fc], acc[fr][fc], 0, 0, 0);
        acc[fr][fc] = __builtin_amdgcn_mfma_f32_16x16x32_bf16(al[fr], bh[fc], acc[fr][fc], 0, 0, 0);
      }
  }
  const int cq = lane >> 4, cc = lane & 15;
  #pragma unroll
  for (int fr = 0; fr < 2; ++fr) {
    #pragma unroll
    for (int fc = 0; fc < 2; ++fc) {
      const int rb = bm + wr + fr * 16 + cq * 4;
      const int col = bn + wc + fc * 16 + cc;
      const float bb = BIAS ? bias[col] : 0.f;
      float* cp = C + (size_t)rb * HID + col;
      #pragma unroll
      for (int e = 0; e < 4; ++e) {
        float v = acc[fr][fc][e] + bb;
        if (ACT == 1) v = fmaxf(v, 0.f);
        cp[(size_t)e * HID] = v;
      }
    }
  }
}

// ---------------------------------------------------------------------------
// Coalesced BatchNorm, 3 stages.
// ---------------------------------------------------------------------------
__global__ __launch_bounds__(256) void bn_stats_kernel(const float* __restrict__ F,
    float* __restrict__ ps, float* __restrict__ ps2) {
  const int b = blockIdx.x, t = threadIdx.x;
  float s = 0.f, s2 = 0.f;
  const float* p = F + (size_t)b * 128 * HID + t;
  for (int r = 0; r < 128; ++r) {
    const float v = p[(size_t)r * HID];
    s += v; s2 += v * v;
  }
  ps[b * HID + t] = s;
  ps2[b * HID + t] = s2;
}

__global__ __launch_bounds__(256) void bn_finalize_kernel(const float* __restrict__ ps,
    const float* __restrict__ ps2, const float* __restrict__ g,
    const float* __restrict__ b, float* __restrict__ scale, float* __restrict__ shift) {
  const int t = threadIdx.x;
  float s = 0.f, s2 = 0.f;
  for (int i = 0; i < 64; ++i) { s += ps[i * HID + t]; s2 += ps2[i * HID + t]; }
  const float mu = s / (float)NROWS;
  const float var = s2 / (float)NROWS - mu * mu;
  const float rstd = rsqrtf(var + 1e-5f);
  const float sc = rstd * g[t];
  scale[t] = sc;
  shift[t] = b[t] - mu * sc;
}

// ---------------------------------------------------------------------------
// Fused bn-apply + L2 rownorm. Emits FN (fp32 fn), Ph (hi-limb fn),
// Fh/Fl (two-limb bn'd feat for gc1).
// ---------------------------------------------------------------------------
__global__ __launch_bounds__(256) void bn_rownorm_kernel(const float* __restrict__ F,
    const float* __restrict__ scale, const float* __restrict__ shift,
    float* __restrict__ FN, ushort* __restrict__ Ph,
    ushort* __restrict__ Fh, ushort* __restrict__ Fl) {
  const int r = blockIdx.x, t = threadIdx.x;
  const float f = F[(size_t)r * HID + t] * scale[t] + shift[t];
  __shared__ float sh[256];
  sh[t] = f * f;
  __syncthreads();
  for (int st = 128; st > 0; st >>= 1) {
    if (t < st) sh[t] += sh[t + st];
    __syncthreads();
  }
  const float inv = 1.0f / fmaxf(sqrtf(sh[0]), 1e-12f);
  const float fn = f * inv;
  const size_t o = (size_t)r * HID + t;
  FN[o] = fn;
  Ph[o] = f2bf(fn);
  const ushort h = f2bf(f);
  Fh[o] = h;
  Fl[o] = f2bf(f - bf2f(h));
}

// ---------------------------------------------------------------------------
// Stripe-free sim: 128x128 tiles of Ph @ Ph^T (K=256 hi-limb MFMA).
// BKS=64 staging (2 blocks+/CU keep load/compute overlap across blocks;
// 8 barrier crossings per pass, 32 MFMA/wave per barrier — R8 paid 16
// crossings at 16 MFMA each; R9's full-K 1-block/CU variant serialized).
// PASS 0: epilogue reduces tile to per-row tile-max (self-excluded) -> M.
// PASS 1: recompute tile; lanes append register values >= tau[row] to the
//         per-row global candidate list (device atomics; ~30 hits/row total).
// Sim values never touch HBM.
// ---------------------------------------------------------------------------
template<int PASS>
__global__ __launch_bounds__(256) void simtile_kernel(const ushort* __restrict__ P,
    float* __restrict__ M, const float* __restrict__ tauv,
    int* __restrict__ gcnt, int* __restrict__ gidx) {
  __shared__ ushort As[TM * BKS];   // 16 KB
  __shared__ ushort Bs[TN * BKS];   // 16 KB
  __shared__ float Ml[2][TM];
  __shared__ float taul[TM];
  const int tid = threadIdx.x;
  const int wave = tid >> 6, lane = tid & 63;
  const int bm = blockIdx.y * TM;
  const int bn = blockIdx.x * TN;
  const int wr = (wave >> 1) * 64;
  const int wc = (wave & 1) * 64;

  if (PASS == 1 && tid < TM) taul[tid] = tauv[bm + tid];

  // staging: 1024 slots of 8 ushorts per tile; slot s: m=s>>3, kg=(s&7)^(m&7)
  const ushort* pa[4];
  const ushort* pb[4];
  #pragma unroll
  for (int j = 0; j < 4; ++j) {
    const int s = tid + j * 256;
    const int m = s >> 3;
    const int kg = (s & 7) ^ (m & 7);
    pa[j] = P + (size_t)(bm + m) * HID + kg * 8;
    pb[j] = P + (size_t)(bn + m) * HID + kg * 8;
  }

  f32x4 acc[4][4];
  const f32x4 zero = {0.f, 0.f, 0.f, 0.f};
  #pragma unroll
  for (int i = 0; i < 4; ++i)
    #pragma unroll
    for (int j = 0; j < 4; ++j) acc[i][j] = zero;

  for (int k0 = 0; k0 < HID; k0 += BKS) {
    __syncthreads();
    #pragma unroll
    for (int j = 0; j < 4; ++j) {
      load_lds16(pa[j] + k0, &As[(tid + j * 256) * 8]);
      load_lds16(pb[j] + k0, &Bs[(tid + j * 256) * 8]);
    }
    __syncthreads();
    #pragma unroll
    for (int h = 0; h < 2; ++h) {
      const int kgb = h * 4 + (lane >> 4);
      bf16x8 af[4], bf[4];
      #pragma unroll
      for (int f = 0; f < 4; ++f) {
        const int m = wr + f * 16 + (lane & 15);
        const int sa = m * 8 + (kgb ^ (m & 7));
        af[f] = *(const bf16x8*)&As[sa * 8];
        const int n = wc + f * 16 + (lane & 15);
        const int sb = n * 8 + (kgb ^ (n & 7));
        bf[f] = *(const bf16x8*)&Bs[sb * 8];
      }
      #pragma unroll
      for (int fr = 0; fr < 4; ++fr)
        #pragma unroll
        for (int fc = 0; fc < 4; ++fc)
          acc[fr][fc] = __builtin_amdgcn_mfma_f32_16x16x32_bf16(af[fr], bf[fc], acc[fr][fc], 0, 0, 0);
    }
  }

  const int cq = lane >> 4, cc = lane & 15;
  if (PASS == 0) {
    #pragma unroll
    for (int fr = 0; fr < 4; ++fr) {
      #pragma unroll
      for (int e = 0; e < 4; ++e) {
        const int lrow = wr + fr * 16 + cq * 4 + e;
        const int grow = bm + lrow;
        float mx = -FLT_MAX;
        #pragma unroll
        for (int fc = 0; fc < 4; ++fc) {
          const int col = bn + wc + fc * 16 + cc;
          mx = fmaxf(mx, (col == grow) ? -FLT_MAX : acc[fr][fc][e]);
        }
        #pragma unroll
        for (int s = 1; s < 16; s <<= 1) mx = fmaxf(mx, __shfl_xor(mx, s));
        if (cc == 0) Ml[wave & 1][lrow] = mx;
      }
    }
    __syncthreads();
    if (tid < TM) M[(size_t)(bm + tid) * 64 + blockIdx.x] = fmaxf(Ml[0][tid], Ml[1][tid]);
  } else {
    #pragma unroll
    for (int fr = 0; fr < 4; ++fr) {
      #pragma unroll
      for (int e = 0; e < 4; ++e) {
        const int lrow = wr + fr * 16 + cq * 4 + e;
        const int grow = bm + lrow;
        const float t = taul[lrow];
        #pragma unroll
        for (int fc = 0; fc < 4; ++fc) {
          const int col = bn + wc + fc * 16 + cc;
          const float v = acc[fr][fc][e];
          if (col != grow && v >= t) {
            const int pos = atomicAdd(&gcnt[grow], 1);
            if (pos < CAP) gidx[(size_t)grow * CAP + pos] = col;
          }
        }
      }
    }
  }
}

// ---------------------------------------------------------------------------
// tau[row] = 16th largest of the 64 tile-maxes (valid top-16 lower bound:
// the top-16 tiles' maxes are 16 distinct non-self elements >= tau).
// Also zeroes gcnt (ws is re-poisoned before every launch).
// ---------------------------------------------------------------------------
__global__ __launch_bounds__(256) void tau_kernel(const float* __restrict__ M,
    float* __restrict__ tauv, int* __restrict__ gcnt) {
  const int wave = threadIdx.x >> 6, lane = threadIdx.x & 63;
  const int row = blockIdx.x * 4 + wave;
  float cur = M[(size_t)row * 64 + lane];
  float tau = cur;
  #pragma unroll
  for (int sel = 0; sel < 16; ++sel) {
    float bv = cur;
    int bl = lane;
    #pragma unroll
    for (int s = 1; s < 64; s <<= 1) {
      const float ov = __shfl_xor(bv, s);
      const int ol = __shfl_xor(bl, s);
      if (ov > bv || (ov == bv && ol < bl)) { bv = ov; bl = ol; }
    }
    tau = bv;
    if (lane == bl) cur = -FLT_MAX;
  }
  if (lane == 0) { tauv[row] = tau; gcnt[row] = 0; }
}

// ---------------------------------------------------------------------------
// Exact refinement: fp32 dots for all candidates, exact top-10, L1-normalize.
// One wave per row.
// ---------------------------------------------------------------------------
__global__ __launch_bounds__(256) void refine_kernel(const int* __restrict__ gcnt,
    const int* __restrict__ gidx, const float* __restrict__ FN,
    int* __restrict__ nidx, float* __restrict__ nval, float* __restrict__ dinv) {
  const int wave = threadIdx.x >> 6, lane = threadIdx.x & 63;
  const int row = blockIdx.x * 4 + wave;
  const int cnt = min(gcnt[row], CAP);
  __shared__ float fnrow[4][HID];
  __shared__ float ev[4][CAP];
  ((float4*)fnrow[wave])[lane] = ((const float4*)(FN + (size_t)row * HID))[lane];
  __syncthreads();
  const int c = lane >> 2, q4 = lane & 3;
  for (int b0 = 0; b0 < cnt; b0 += 16) {
    const int ci = b0 + c;
    const int cand = (ci < cnt) ? gidx[(size_t)row * CAP + ci] : 0;
    float s = 0.f;
    const float* fc = FN + (size_t)cand * HID + q4 * 64;
    const float* fr = fnrow[wave] + q4 * 64;
    #pragma unroll 8
    for (int k = 0; k < 64; ++k) s += fr[k] * fc[k];
    s += __shfl_xor(s, 1);
    s += __shfl_xor(s, 2);
    if (q4 == 0 && ci < cnt) ev[wave][ci] = s;
  }
  __syncthreads();
  float outv[TOPK];
  int outi[TOPK];
  float sum = 1.0f;  // diag contributes 1
  #pragma unroll
  for (int sel = 0; sel < TOPK; ++sel) {
    float bv = -FLT_MAX;
    int bp = 0;
    #pragma unroll
    for (int j = 0; j < 4; ++j) {
      const int p = lane + j * 64;
      if (p < cnt) {
        const float v = ev[wave][p];
        if (v > bv) { bv = v; bp = p; }
      }
    }
    #pragma unroll
    for (int s = 1; s < 64; s <<= 1) {
      const float ov = __shfl_xor(bv, s);
      const int op = __shfl_xor(bp, s);
      if (ov > bv || (ov == bv && op < bp)) { bv = ov; bp = op; }
    }
    outv[sel] = bv;
    outi[sel] = bp;
    sum += fabsf(bv);
    if (lane == 0) ev[wave][bp] = -FLT_MAX;
  }
  if (lane == 0) {
    const float inv = 1.0f / fmaxf(sum, 1e-12f);
    dinv[row] = inv;
    #pragma unroll
    for (int sel = 0; sel < TOPK; ++sel) {
      nval[row * TOPK + sel] = outv[sel] * inv;
      nidx[row * TOPK + sel] = gidx[(size_t)row * CAP + outi[sel]];
    }
  }
}

// ---------------------------------------------------------------------------
// Sparse adj (11 nnz/row) @ T + bias, leaky_relu(0.25).
// EMIT=0: write fp32 H. EMIT=1: write two-limb bf16 planes (next gemm's A).
// ---------------------------------------------------------------------------
template<int EMIT>
__global__ __launch_bounds__(256) void spmm_kernel(const float* __restrict__ T,
    const int* __restrict__ nidx, const float* __restrict__ nval,
    const float* __restrict__ dinv, const float* __restrict__ bias,
    float* __restrict__ H, ushort* __restrict__ Hh, ushort* __restrict__ Hl) {
  const int r = blockIdx.x, c = threadIdx.x;
  float acc = dinv[r] * T[(size_t)r * HID + c];
  #pragma unroll
  for (int n = 0; n < TOPK; ++n) {
    acc += nval[r * TOPK + n] * T[(size_t)nidx[r * TOPK + n] * HID + c];
  }
  acc += bias[c];
  const float v = acc >= 0.f ? acc : 0.25f * acc;
  const size_t o = (size_t)r * HID + c;
  if (EMIT == 0) {
    H[o] = v;
  } else {
    const ushort h = f2bf(v);
    Hh[o] = h;
    Hl[o] = f2bf(v - bf2f(h));
  }
}

__global__ __launch_bounds__(256) void clf_kernel(const float* __restrict__ H,
    const float* __restrict__ W, const float* __restrict__ b,
    float* __restrict__ L) {
  const int id = blockIdx.x * 256 + threadIdx.x;
  if (id >= NROWS * NCLS) return;
  const int r = id / NCLS, c = id % NCLS;
  float s = b[c];
  const float* hr = H + (size_t)r * HID;
  for (int k = 0; k < HID; ++k) s += hr[k] * W[k * NCLS + c];
  L[id] = s;
}

__global__ __launch_bounds__(256) void fuse_kernel(const float* __restrict__ L,
    const float* __restrict__ attn, float* __restrict__ fused) {
  const int id = blockIdx.x * 256 + threadIdx.x;
  if (id >= NROWS * NCLS) return;
  const float a0 = attn[0], a1 = attn[1], a2 = attn[2];
  const float m = fmaxf(a0, fmaxf(a1, a2));
  const float e0 = expf(a0 - m), e1 = expf(a1 - m), e2 = expf(a2 - m);
  const float inv = 1.0f / (e0 + e1 + e2);
  const float l0 = L[id];
  const float l1 = L[NROWS * NCLS + id];
  const float l2 = L[2 * NROWS * NCLS + id];
  const float s0 = 1.0f / (1.0f + expf(-l0));
  const float s1 = 1.0f / (1.0f + expf(-l1));
  const float s2 = 1.0f / (1.0f + expf(-l2));
  fused[id] = (e0 * s0 + e1 * s1 + e2 * s2) * inv;
}

__global__ __launch_bounds__(128) void head_kernel(const float* __restrict__ fused,
    const float* __restrict__ W1, const float* __restrict__ b1,
    const float* __restrict__ W2, const float* __restrict__ b2,
    float* __restrict__ out) {
  const int r = blockIdx.x, t = threadIdx.x;
  __shared__ float f[NCLS];
  __shared__ float hh[128];
  if (t < NCLS) f[t] = fused[r * NCLS + t];
  __syncthreads();
  float s = b1[t];
  #pragma unroll
  for (int k = 0; k < NCLS; ++k) s += f[k] * W1[k * 128 + t];
  hh[t] = s >= 0.f ? s : 0.25f * s;
  __syncthreads();
  if (t < NCLS) {
    float o = b2[t];
    for (int k = 0; k < 128; ++k) o += hh[k] * W2[k * NCLS + t];
    out[r * NCLS + t] = o;
  }
}

// ---------------------------------------------------------------------------
extern "C" void kernel_launch(void* const* d_in, const int* in_sizes, int n_in,
                              void* d_out, int out_size, void* d_ws, size_t ws_size,
                              hipStream_t stream) {
  const float* x[3]    = {(const float*)d_in[0], (const float*)d_in[1], (const float*)d_in[2]};
  const float* encW[3] = {(const float*)d_in[3], (const float*)d_in[4], (const float*)d_in[5]};
  const float* enc_b = (const float*)d_in[6];
  const float* bn_g  = (const float*)d_in[7];
  const float* bn_b  = (const float*)d_in[8];
  const float* gc1W  = (const float*)d_in[9];
  const float* gc1b  = (const float*)d_in[10];
  const float* gc2W  = (const float*)d_in[11];
  const float* gc2b  = (const float*)d_in[12];
  const float* clfW  = (const float*)d_in[13];
  const float* clfb  = (const float*)d_in[14];
  const float* attn  = (const float*)d_in[15];
  const float* f1W   = (const float*)d_in[16];
  const float* f1b   = (const float*)d_in[17];
  const float* f2W   = (const float*)d_in[18];
  const float* f2b   = (const float*)d_in[19];
  float* out = (float*)d_out;

  // Workspace layout
  const size_t NH = (size_t)NROWS * HID;
  float* ws = (float*)d_ws;
  float* FN = ws;                                  // fp32 fn
  float* A  = FN + NH;                             // encoder out (pre-bn)
  float* C  = A + NH;                              // gemm temp
  float* Bf = C + NH;                              // h2 fp32
  int*   nidx = (int*)(Bf + NH);
  float* nval = (float*)(nidx + (size_t)NROWS * TOPK);
  float* dinv = nval + (size_t)NROWS * TOPK;
  float* logits = dinv + NROWS;
  float* fused = logits + (size_t)3 * NROWS * NCLS;
  float* ps    = fused + (size_t)NROWS * NCLS;     // 64*256
  float* ps2   = ps + 64 * HID;
  float* scale = ps2 + 64 * HID;
  float* shift = scale + HID;
  float* M     = shift + HID;                      // 8192*64 tile maxes
  float* tauv  = M + (size_t)NROWS * 64;           // 8192
  int*   gcnt  = (int*)(tauv + NROWS);             // 8192
  int*   gidx  = gcnt + NROWS;                     // 8192*CAP
  ushort* Ph = (ushort*)(gidx + (size_t)NROWS * CAP);  // hi-limb fn
  ushort* Fh = Ph + NH;                            // gc1 A limbs
  ushort* Fl = Fh + NH;
  ushort* Hh = Fl + NH;                            // gc2 A limbs
  ushort* Hl = Hh + NH;
  ushort* Ah = Hl + NH;                            // encoder A limbs (Kp<=1024)
  ushort* Al = Ah + (size_t)NROWS * 1024;
  ushort* Wh = Al + (size_t)NROWS * 1024;          // B limbs (HID x Kp<=1024)
  ushort* Wl = Wh + (size_t)HID * 1024;

  const dim3 blk(256);
  for (int i = 0; i < 3; ++i) {
    const int D = in_sizes[i] / NROWS;
    int Kp = 256, ksh = 8;
    while (Kp < D) { Kp <<= 1; ksh++; }
    // encoder: pack limbs of x and W^T, then A = relu(x @ W + b)
    packAB_kernel<<<((NROWS + HID) << ksh) / 256, blk, 0, stream>>>(
        x[i], encW[i], Ah, Al, Wh, Wl, D, Kp, ksh);
    limbgemm_kernel<true, 1><<<512, blk, 0, stream>>>(Ah, Al, Wh, Wl,
                                                      enc_b + i * HID, A, Kp);
    // coalesced BN + fused rownorm/limb-emit
    bn_stats_kernel<<<64, blk, 0, stream>>>(A, ps, ps2);
    bn_finalize_kernel<<<1, blk, 0, stream>>>(ps, ps2, bn_g + i * HID, bn_b + i * HID,
                                              scale, shift);
    bn_rownorm_kernel<<<NROWS, blk, 0, stream>>>(A, scale, shift, FN, Ph, Fh, Fl);
    // stripe-free knn graph: tile-max pass -> tau -> compaction pass -> refine
    simtile_kernel<0><<<dim3(64, 64), blk, 0, stream>>>(Ph, M, nullptr, nullptr, nullptr);
    tau_kernel<<<NROWS / 4, blk, 0, stream>>>(M, tauv, gcnt);
    simtile_kernel<1><<<dim3(64, 64), blk, 0, stream>>>(Ph, nullptr, tauv, gcnt, gidx);
    refine_kernel<<<NROWS / 4, blk, 0, stream>>>(gcnt, gidx, FN, nidx, nval, dinv);
    // gc1: C = feat @ W1 (limb MFMA), h1 -> limbs via spmm epilogue
    packW_kernel<<<(HID * HID) / 256, blk, 0, stream>>>(gc1W + (size_t)i * HID * HID, Wh, Wl);
    limbgemm_kernel<false, 0><<<512, blk, 0, stream>>>(Fh, Fl, Wh, Wl, nullptr, C, HID);
    spmm_kernel<1><<<NROWS, blk, 0, stream>>>(C, nidx, nval, dinv, gc1b + i * HID,
                                              nullptr, Hh, Hl);
    // gc2
    packW_kernel<<<(HID * HID) / 256, blk, 0, stream>>>(gc2W + (size_t)i * HID * HID, Wh, Wl);
    limbgemm_kernel<false, 0><<<512, blk, 0, stream>>>(Hh, Hl, Wh, Wl, nullptr, C, HID);
    spmm_kernel<0><<<NROWS, blk, 0, stream>>>(C, nidx, nval, dinv, gc2b + i * HID,
                                              Bf, nullptr, nullptr);
    clf_kernel<<<(NROWS * NCLS + 255) / 256, blk, 0, stream>>>(Bf, clfW + (size_t)i * HID * NCLS,
                                                               clfb + i * NCLS,
                                                               logits + (size_t)i * NROWS * NCLS);
  }
  fuse_kernel<<<(NROWS * NCLS + 255) / 256, blk, 0, stream>>>(logits, attn, fused);
  head_kernel<<<NROWS, dim3(128), 0, stream>>>(fused, f1W, f1b, f2W, f2b, out);
}

// Round 11
// 1024.374 us; speedup vs baseline: 1.4116x; 1.0492x over previous
//
#include <hip/hip_runtime.h>
#include <cfloat>
#include <cstdint>
#include <cstddef>

#define NROWS 8192
#define HID 256
#define NCLS 5
#define TOPK 10
#define CAP 256     // per-row candidate capacity (typ. ~20-60 used)
#define TM 128
#define TN 128
#define BK 32
#define BKS 64      // sim K-step

typedef __bf16 bf16x8 __attribute__((ext_vector_type(8)));
typedef float f32x4 __attribute__((ext_vector_type(4)));

__device__ inline ushort f2bf(float x) {
  unsigned u = __float_as_uint(x);
  unsigned r = (u + 0x7fffu + ((u >> 16) & 1u)) >> 16;  // RNE
  return (ushort)r;
}
__device__ inline float bf2f(ushort b) { return __uint_as_float(((unsigned)b) << 16); }

// async global->LDS 16B/lane; LDS dest is wave-uniform base + lane*16
__device__ __forceinline__ void load_lds16(const void* g, void* l) {
  __builtin_amdgcn_global_load_lds(
      (const __attribute__((address_space(1))) void*)g,
      (__attribute__((address_space(3))) void*)l, 16, 0, 0);
}

// ---------------------------------------------------------------------------
// Encoder pack: X rows (M x D fp32 -> hi/lo bf16 limb planes, K padded to Kp)
// and W (D x HID fp32, transposed -> HID x Kp limb planes).
// ---------------------------------------------------------------------------
__global__ __launch_bounds__(256) void packAB_kernel(const float* __restrict__ X,
    const float* __restrict__ W, ushort* __restrict__ Ah, ushort* __restrict__ Al,
    ushort* __restrict__ Bh, ushort* __restrict__ Bl, int D, int Kp, int ksh) {
  const int id = blockIdx.x * 256 + threadIdx.x;
  const int atotal = NROWS << ksh;
  if (id < atotal) {
    const int r = id >> ksh, k = id & (Kp - 1);
    const float x = (k < D) ? X[(size_t)r * D + k] : 0.f;
    const ushort h = f2bf(x);
    Ah[id] = h;
    Al[id] = f2bf(x - bf2f(h));
  } else {
    const int id2 = id - atotal;
    if (id2 < (HID << ksh)) {
      const int n = id2 >> ksh, k = id2 & (Kp - 1);
      const float x = (k < D) ? W[(size_t)k * HID + n] : 0.f;
      const ushort h = f2bf(x);
      Bh[id2] = h;
      Bl[id2] = f2bf(x - bf2f(h));
    }
  }
}

// ---------------------------------------------------------------------------
// GCN weight pack: W [HID x HID] -> transposed limb planes [HID x 256].
// ---------------------------------------------------------------------------
__global__ __launch_bounds__(256) void packW_kernel(const float* __restrict__ W,
    ushort* __restrict__ Bh, ushort* __restrict__ Bl) {
  const int id = blockIdx.x * 256 + threadIdx.x;  // 65536
  const int k = id >> 8, n = id & 255;            // coalesced read over n
  const float x = W[(size_t)k * HID + n];
  const ushort h = f2bf(x);
  Bh[(size_t)n * HID + k] = h;
  Bl[(size_t)n * HID + k] = f2bf(x - bf2f(h));
}

// ---------------------------------------------------------------------------
// 3-segment two-limb bf16 MFMA GEMM: C[NROWS x HID] = act(A @ B^T + bias).
// Segments hh + hl + lh (ll ~2^-18, dropped). 64x64 tile, 4 waves (2x2),
// XCD-swizzled 1-D grid for A-tile L2 reuse.
// ---------------------------------------------------------------------------
template<bool BIAS, int ACT>
__global__ __launch_bounds__(256) void limbgemm_kernel(const ushort* __restrict__ Ah,
    const ushort* __restrict__ Al, const ushort* __restrict__ Bh,
    const ushort* __restrict__ Bl, const float* __restrict__ bias,
    float* __restrict__ C, int Kp) {
  __shared__ ushort AsH[64 * BK], AsL[64 * BK], BsH[64 * BK], BsL[64 * BK];
  const int tid = threadIdx.x;
  const int wave = tid >> 6, lane = tid & 63;
  const int bid = blockIdx.x;
  const int xcd = bid & 7, slot = bid >> 3;
  const int bxi = slot & 3;
  const int byi = xcd * 16 + (slot >> 2);
  const int bm = byi * 64, bn = bxi * 64;
  const int wr = (wave >> 1) * 32, wc = (wave & 1) * 32;

  f32x4 acc[2][2];
  const f32x4 zero = {0.f, 0.f, 0.f, 0.f};
  acc[0][0] = zero; acc[0][1] = zero; acc[1][0] = zero; acc[1][1] = zero;

  const int r0 = tid >> 2, kl0 = (tid & 3) ^ ((r0 & 3) ^ ((r0 >> 2) & 1));
  const size_t aoff = (size_t)(bm + r0) * Kp + kl0 * 8;
  const size_t boff = (size_t)(bn + r0) * Kp + kl0 * 8;

  for (int k0 = 0; k0 < Kp; k0 += BK) {
    __syncthreads();
    load_lds16(Ah + aoff + k0, &AsH[tid * 8]);
    load_lds16(Al + aoff + k0, &AsL[tid * 8]);
    load_lds16(Bh + boff + k0, &BsH[tid * 8]);
    load_lds16(Bl + boff + k0, &BsL[tid * 8]);
    __syncthreads();
    bf16x8 ah[2], al[2], bh[2], bl[2];
    const int kg = lane >> 4;
    #pragma unroll
    for (int f = 0; f < 2; ++f) {
      const int m = wr + f * 16 + (lane & 15);
      const int sa = m * 4 + (kg ^ (m & 3) ^ ((m >> 2) & 1));
      ah[f] = *(const bf16x8*)&AsH[sa * 8];
      al[f] = *(const bf16x8*)&AsL[sa * 8];
      const int n = wc + f * 16 + (lane & 15);
      const int sb = n * 4 + (kg ^ (n & 3) ^ ((n >> 2) & 1));
      bh[f] = *(const bf16x8*)&BsH[sb * 8];
      bl[f] = *(const bf16x8*)&BsL[sb * 8];
    }
    #pragma unroll
    for (int fr = 0; fr < 2; ++fr)
      #pragma unroll
      for (int fc = 0; fc < 2; ++fc) {
        acc[fr][fc] = __builtin_amdgcn_mfma_f32_16x16x32_bf16(ah[fr], bh[fc], acc[fr][fc], 0, 0, 0);
        acc[fr][fc] = __builtin_amdgcn_mfma_f32_16x16x32_bf16(ah[fr], bl[fc], acc[fr][fc], 0, 0, 0);
        acc[fr][fc] = __builtin_amdgcn_mfma_f32_16x16x32_bf16(al[fr], bh[fc], acc[fr][fc], 0, 0, 0);
      }
  }
  const int cq = lane >> 4, cc = lane & 15;
  #pragma unroll
  for (int fr = 0; fr < 2; ++fr) {
    #pragma unroll
    for (int fc = 0; fc < 2; ++fc) {
      const int rb = bm + wr + fr * 16 + cq * 4;
      const int col = bn + wc + fc * 16 + cc;
      const float bb = BIAS ? bias[col] : 0.f;
      float* cp = C + (size_t)rb * HID + col;
      #pragma unroll
      for (int e = 0; e < 4; ++e) {
        float v = acc[fr][fc][e] + bb;
        if (ACT == 1) v = fmaxf(v, 0.f);
        cp[(size_t)e * HID] = v;
      }
    }
  }
}

// ---------------------------------------------------------------------------
// Coalesced BatchNorm, 3 stages.
// ---------------------------------------------------------------------------
__global__ __launch_bounds__(256) void bn_stats_kernel(const float* __restrict__ F,
    float* __restrict__ ps, float* __restrict__ ps2) {
  const int b = blockIdx.x, t = threadIdx.x;
  float s = 0.f, s2 = 0.f;
  const float* p = F + (size_t)b * 128 * HID + t;
  for (int r = 0; r < 128; ++r) {
    const float v = p[(size_t)r * HID];
    s += v; s2 += v * v;
  }
  ps[b * HID + t] = s;
  ps2[b * HID + t] = s2;
}

__global__ __launch_bounds__(256) void bn_finalize_kernel(const float* __restrict__ ps,
    const float* __restrict__ ps2, const float* __restrict__ g,
    const float* __restrict__ b, float* __restrict__ scale, float* __restrict__ shift) {
  const int t = threadIdx.x;
  float s = 0.f, s2 = 0.f;
  for (int i = 0; i < 64; ++i) { s += ps[i * HID + t]; s2 += ps2[i * HID + t]; }
  const float mu = s / (float)NROWS;
  const float var = s2 / (float)NROWS - mu * mu;
  const float rstd = rsqrtf(var + 1e-5f);
  const float sc = rstd * g[t];
  scale[t] = sc;
  shift[t] = b[t] - mu * sc;
}

// ---------------------------------------------------------------------------
// Fused bn-apply + L2 rownorm. Emits FN (fp32 fn), Ph (hi-limb fn),
// Fh/Fl (two-limb bn'd feat for gc1).
// ---------------------------------------------------------------------------
__global__ __launch_bounds__(256) void bn_rownorm_kernel(const float* __restrict__ F,
    const float* __restrict__ scale, const float* __restrict__ shift,
    float* __restrict__ FN, ushort* __restrict__ Ph,
    ushort* __restrict__ Fh, ushort* __restrict__ Fl) {
  const int r = blockIdx.x, t = threadIdx.x;
  const float f = F[(size_t)r * HID + t] * scale[t] + shift[t];
  __shared__ float sh[256];
  sh[t] = f * f;
  __syncthreads();
  for (int st = 128; st > 0; st >>= 1) {
    if (t < st) sh[t] += sh[t + st];
    __syncthreads();
  }
  const float inv = 1.0f / fmaxf(sqrtf(sh[0]), 1e-12f);
  const float fn = f * inv;
  const size_t o = (size_t)r * HID + t;
  FN[o] = fn;
  Ph[o] = f2bf(fn);
  const ushort h = f2bf(f);
  Fh[o] = h;
  Fl[o] = f2bf(f - bf2f(h));
}

// ---------------------------------------------------------------------------
// Stripe-free sim: 128x128 tiles of Ph @ Ph^T (K=256 hi-limb MFMA).
// 512 threads / 8 waves, each wave a 32x64 sub-tile (acc[2][4] = 32 AGPR
// vs R10's 64) -> ~2x waves/CU residency for latency hiding. BKS=64.
// PASS 0: epilogue reduces tile to per-row tile-max (self-excluded) -> M.
// PASS 1: recompute tile; lanes append register values >= tau[row] to the
//         per-row global candidate list (device atomics; ~30 hits/row total).
// Sim values never touch HBM.
// ---------------------------------------------------------------------------
template<int PASS>
__global__ __launch_bounds__(512) void simtile_kernel(const ushort* __restrict__ P,
    float* __restrict__ M, const float* __restrict__ tauv,
    int* __restrict__ gcnt, int* __restrict__ gidx) {
  __shared__ ushort As[TM * BKS];   // 16 KB
  __shared__ ushort Bs[TN * BKS];   // 16 KB
  __shared__ float Ml[2][TM];
  __shared__ float taul[TM];
  const int tid = threadIdx.x;
  const int wave = tid >> 6, lane = tid & 63;
  const int bm = blockIdx.y * TM;
  const int bn = blockIdx.x * TN;
  const int wr = (wave >> 1) * 32;   // 4 row-bands of 32
  const int wc = (wave & 1) * 64;    // 2 col-halves of 64

  if (PASS == 1 && tid < TM) taul[tid] = tauv[bm + tid];

  // staging: 1024 slots of 8 ushorts per tile; slot s: m=s>>3, kg=(s&7)^(m&7)
  const ushort* pa[2];
  const ushort* pb[2];
  #pragma unroll
  for (int j = 0; j < 2; ++j) {
    const int s = tid + j * 512;
    const int m = s >> 3;
    const int kg = (s & 7) ^ (m & 7);
    pa[j] = P + (size_t)(bm + m) * HID + kg * 8;
    pb[j] = P + (size_t)(bn + m) * HID + kg * 8;
  }

  f32x4 acc[2][4];
  const f32x4 zero = {0.f, 0.f, 0.f, 0.f};
  #pragma unroll
  for (int i = 0; i < 2; ++i)
    #pragma unroll
    for (int j = 0; j < 4; ++j) acc[i][j] = zero;

  for (int k0 = 0; k0 < HID; k0 += BKS) {
    __syncthreads();
    #pragma unroll
    for (int j = 0; j < 2; ++j) {
      load_lds16(pa[j] + k0, &As[(tid + j * 512) * 8]);
      load_lds16(pb[j] + k0, &Bs[(tid + j * 512) * 8]);
    }
    __syncthreads();
    #pragma unroll
    for (int h = 0; h < 2; ++h) {
      const int kgb = h * 4 + (lane >> 4);
      bf16x8 af[2], bf[4];
      #pragma unroll
      for (int f = 0; f < 2; ++f) {
        const int m = wr + f * 16 + (lane & 15);
        const int sa = m * 8 + (kgb ^ (m & 7));
        af[f] = *(const bf16x8*)&As[sa * 8];
      }
      #pragma unroll
      for (int f = 0; f < 4; ++f) {
        const int n = wc + f * 16 + (lane & 15);
        const int sb = n * 8 + (kgb ^ (n & 7));
        bf[f] = *(const bf16x8*)&Bs[sb * 8];
      }
      #pragma unroll
      for (int fr = 0; fr < 2; ++fr)
        #pragma unroll
        for (int fc = 0; fc < 4; ++fc)
          acc[fr][fc] = __builtin_amdgcn_mfma_f32_16x16x32_bf16(af[fr], bf[fc], acc[fr][fc], 0, 0, 0);
    }
  }

  const int cq = lane >> 4, cc = lane & 15;
  if (PASS == 0) {
    #pragma unroll
    for (int fr = 0; fr < 2; ++fr) {
      #pragma unroll
      for (int e = 0; e < 4; ++e) {
        const int lrow = wr + fr * 16 + cq * 4 + e;
        const int grow = bm + lrow;
        float mx = -FLT_MAX;
        #pragma unroll
        for (int fc = 0; fc < 4; ++fc) {
          const int col = bn + wc + fc * 16 + cc;
          mx = fmaxf(mx, (col == grow) ? -FLT_MAX : acc[fr][fc][e]);
        }
        #pragma unroll
        for (int s = 1; s < 16; s <<= 1) mx = fmaxf(mx, __shfl_xor(mx, s));
        if (cc == 0) Ml[wave & 1][lrow] = mx;
      }
    }
    __syncthreads();
    if (tid < TM) M[(size_t)(bm + tid) * 64 + blockIdx.x] = fmaxf(Ml[0][tid], Ml[1][tid]);
  } else {
    #pragma unroll
    for (int fr = 0; fr < 2; ++fr) {
      #pragma unroll
      for (int e = 0; e < 4; ++e) {
        const int lrow = wr + fr * 16 + cq * 4 + e;
        const int grow = bm + lrow;
        const float t = taul[lrow];
        #pragma unroll
        for (int fc = 0; fc < 4; ++fc) {
          const int col = bn + wc + fc * 16 + cc;
          const float v = acc[fr][fc][e];
          if (col != grow && v >= t) {
            const int pos = atomicAdd(&gcnt[grow], 1);
            if (pos < CAP) gidx[(size_t)grow * CAP + pos] = col;
          }
        }
      }
    }
  }
}

// ---------------------------------------------------------------------------
// tau[row] = 16th largest of the 64 tile-maxes (valid top-16 lower bound:
// the top-16 tiles' maxes are 16 distinct non-self elements >= tau).
// Also zeroes gcnt (ws is re-poisoned before every launch).
// ---------------------------------------------------------------------------
__global__ __launch_bounds__(256) void tau_kernel(const float* __restrict__ M,
    float* __restrict__ tauv, int* __restrict__ gcnt) {
  const int wave = threadIdx.x >> 6, lane = threadIdx.x & 63;
  const int row = blockIdx.x * 4 + wave;
  float cur = M[(size_t)row * 64 + lane];
  float tau = cur;
  #pragma unroll
  for (int sel = 0; sel < 16; ++sel) {
    float bv = cur;
    int bl = lane;
    #pragma unroll
    for (int s = 1; s < 64; s <<= 1) {
      const float ov = __shfl_xor(bv, s);
      const int ol = __shfl_xor(bl, s);
      if (ov > bv || (ov == bv && ol < bl)) { bv = ov; bl = ol; }
    }
    tau = bv;
    if (lane == bl) cur = -FLT_MAX;
  }
  if (lane == 0) { tauv[row] = tau; gcnt[row] = 0; }
}

// ---------------------------------------------------------------------------
// Exact refinement: fp32 dots for all candidates, exact top-10, L1-normalize.
// One wave per row.
// ---------------------------------------------------------------------------
__global__ __launch_bounds__(256) void refine_kernel(const int* __restrict__ gcnt,
    const int* __restrict__ gidx, const float* __restrict__ FN,
    int* __restrict__ nidx, float* __restrict__ nval, float* __restrict__ dinv) {
  const int wave = threadIdx.x >> 6, lane = threadIdx.x & 63;
  const int row = blockIdx.x * 4 + wave;
  const int cnt = min(gcnt[row], CAP);
  __shared__ float fnrow[4][HID];
  __shared__ float ev[4][CAP];
  ((float4*)fnrow[wave])[lane] = ((const float4*)(FN + (size_t)row * HID))[lane];
  __syncthreads();
  const int c = lane >> 2, q4 = lane & 3;
  for (int b0 = 0; b0 < cnt; b0 += 16) {
    const int ci = b0 + c;
    const int cand = (ci < cnt) ? gidx[(size_t)row * CAP + ci] : 0;
    float s = 0.f;
    const float* fc = FN + (size_t)cand * HID + q4 * 64;
    const float* fr = fnrow[wave] + q4 * 64;
    #pragma unroll 8
    for (int k = 0; k < 64; ++k) s += fr[k] * fc[k];
    s += __shfl_xor(s, 1);
    s += __shfl_xor(s, 2);
    if (q4 == 0 && ci < cnt) ev[wave][ci] = s;
  }
  __syncthreads();
  float outv[TOPK];
  int outi[TOPK];
  float sum = 1.0f;  // diag contributes 1
  #pragma unroll
  for (int sel = 0; sel < TOPK; ++sel) {
    float bv = -FLT_MAX;
    int bp = 0;
    #pragma unroll
    for (int j = 0; j < 4; ++j) {
      const int p = lane + j * 64;
      if (p < cnt) {
        const float v = ev[wave][p];
        if (v > bv) { bv = v; bp = p; }
      }
    }
    #pragma unroll
    for (int s = 1; s < 64; s <<= 1) {
      const float ov = __shfl_xor(bv, s);
      const int op = __shfl_xor(bp, s);
      if (ov > bv || (ov == bv && op < bp)) { bv = ov; bp = op; }
    }
    outv[sel] = bv;
    outi[sel] = bp;
    sum += fabsf(bv);
    if (lane == 0) ev[wave][bp] = -FLT_MAX;
  }
  if (lane == 0) {
    const float inv = 1.0f / fmaxf(sum, 1e-12f);
    dinv[row] = inv;
    #pragma unroll
    for (int sel = 0; sel < TOPK; ++sel) {
      nval[row * TOPK + sel] = outv[sel] * inv;
      nidx[row * TOPK + sel] = gidx[(size_t)row * CAP + outi[sel]];
    }
  }
}

// ---------------------------------------------------------------------------
// Sparse adj (11 nnz/row) @ T + bias, leaky_relu(0.25).
// EMIT=0: write fp32 H. EMIT=1: write two-limb bf16 planes (next gemm's A).
// ---------------------------------------------------------------------------
template<int EMIT>
__global__ __launch_bounds__(256) void spmm_kernel(const float* __restrict__ T,
    const int* __restrict__ nidx, const float* __restrict__ nval,
    const float* __restrict__ dinv, const float* __restrict__ bias,
    float* __restrict__ H, ushort* __restrict__ Hh, ushort* __restrict__ Hl) {
  const int r = blockIdx.x, c = threadIdx.x;
  float acc = dinv[r] * T[(size_t)r * HID + c];
  #pragma unroll
  for (int n = 0; n < TOPK; ++n) {
    acc += nval[r * TOPK + n] * T[(size_t)nidx[r * TOPK + n] * HID + c];
  }
  acc += bias[c];
  const float v = acc >= 0.f ? acc : 0.25f * acc;
  const size_t o = (size_t)r * HID + c;
  if (EMIT == 0) {
    H[o] = v;
  } else {
    const ushort h = f2bf(v);
    Hh[o] = h;
    Hl[o] = f2bf(v - bf2f(h));
  }
}

__global__ __launch_bounds__(256) void clf_kernel(const float* __restrict__ H,
    const float* __restrict__ W, const float* __restrict__ b,
    float* __restrict__ L) {
  const int id = blockIdx.x * 256 + threadIdx.x;
  if (id >= NROWS * NCLS) return;
  const int r = id / NCLS, c = id % NCLS;
  float s = b[c];
  const float* hr = H + (size_t)r * HID;
  for (int k = 0; k < HID; ++k) s += hr[k] * W[k * NCLS + c];
  L[id] = s;
}

__global__ __launch_bounds__(256) void fuse_kernel(const float* __restrict__ L,
    const float* __restrict__ attn, float* __restrict__ fused) {
  const int id = blockIdx.x * 256 + threadIdx.x;
  if (id >= NROWS * NCLS) return;
  const float a0 = attn[0], a1 = attn[1], a2 = attn[2];
  const float m = fmaxf(a0, fmaxf(a1, a2));
  const float e0 = expf(a0 - m), e1 = expf(a1 - m), e2 = expf(a2 - m);
  const float inv = 1.0f / (e0 + e1 + e2);
  const float l0 = L[id];
  const float l1 = L[NROWS * NCLS + id];
  const float l2 = L[2 * NROWS * NCLS + id];
  const float s0 = 1.0f / (1.0f + expf(-l0));
  const float s1 = 1.0f / (1.0f + expf(-l1));
  const float s2 = 1.0f / (1.0f + expf(-l2));
  fused[id] = (e0 * s0 + e1 * s1 + e2 * s2) * inv;
}

__global__ __launch_bounds__(128) void head_kernel(const float* __restrict__ fused,
    const float* __restrict__ W1, const float* __restrict__ b1,
    const float* __restrict__ W2, const float* __restrict__ b2,
    float* __restrict__ out) {
  const int r = blockIdx.x, t = threadIdx.x;
  __shared__ float f[NCLS];
  __shared__ float hh[128];
  if (t < NCLS) f[t] = fused[r * NCLS + t];
  __syncthreads();
  float s = b1[t];
  #pragma unroll
  for (int k = 0; k < NCLS; ++k) s += f[k] * W1[k * 128 + t];
  hh[t] = s >= 0.f ? s : 0.25f * s;
  __syncthreads();
  if (t < NCLS) {
    float o = b2[t];
    for (int k = 0; k < 128; ++k) o += hh[k] * W2[k * NCLS + t];
    out[r * NCLS + t] = o;
  }
}

// ---------------------------------------------------------------------------
extern "C" void kernel_launch(void* const* d_in, const int* in_sizes, int n_in,
                              void* d_out, int out_size, void* d_ws, size_t ws_size,
                              hipStream_t stream) {
  const float* x[3]    = {(const float*)d_in[0], (const float*)d_in[1], (const float*)d_in[2]};
  const float* encW[3] = {(const float*)d_in[3], (const float*)d_in[4], (const float*)d_in[5]};
  const float* enc_b = (const float*)d_in[6];
  const float* bn_g  = (const float*)d_in[7];
  const float* bn_b  = (const float*)d_in[8];
  const float* gc1W  = (const float*)d_in[9];
  const float* gc1b  = (const float*)d_in[10];
  const float* gc2W  = (const float*)d_in[11];
  const float* gc2b  = (const float*)d_in[12];
  const float* clfW  = (const float*)d_in[13];
  const float* clfb  = (const float*)d_in[14];
  const float* attn  = (const float*)d_in[15];
  const float* f1W   = (const float*)d_in[16];
  const float* f1b   = (const float*)d_in[17];
  const float* f2W   = (const float*)d_in[18];
  const float* f2b   = (const float*)d_in[19];
  float* out = (float*)d_out;

  // Workspace layout
  const size_t NH = (size_t)NROWS * HID;
  float* ws = (float*)d_ws;
  float* FN = ws;                                  // fp32 fn
  float* A  = FN + NH;                             // encoder out (pre-bn)
  float* C  = A + NH;                              // gemm temp
  float* Bf = C + NH;                              // h2 fp32
  int*   nidx = (int*)(Bf + NH);
  float* nval = (float*)(nidx + (size_t)NROWS * TOPK);
  float* dinv = nval + (size_t)NROWS * TOPK;
  float* logits = dinv + NROWS;
  float* fused = logits + (size_t)3 * NROWS * NCLS;
  float* ps    = fused + (size_t)NROWS * NCLS;     // 64*256
  float* ps2   = ps + 64 * HID;
  float* scale = ps2 + 64 * HID;
  float* shift = scale + HID;
  float* M     = shift + HID;                      // 8192*64 tile maxes
  float* tauv  = M + (size_t)NROWS * 64;           // 8192
  int*   gcnt  = (int*)(tauv + NROWS);             // 8192
  int*   gidx  = gcnt + NROWS;                     // 8192*CAP
  ushort* Ph = (ushort*)(gidx + (size_t)NROWS * CAP);  // hi-limb fn
  ushort* Fh = Ph + NH;                            // gc1 A limbs
  ushort* Fl = Fh + NH;
  ushort* Hh = Fl + NH;                            // gc2 A limbs
  ushort* Hl = Hh + NH;
  ushort* Ah = Hl + NH;                            // encoder A limbs (Kp<=1024)
  ushort* Al = Ah + (size_t)NROWS * 1024;
  ushort* Wh = Al + (size_t)NROWS * 1024;          // B limbs (HID x Kp<=1024)
  ushort* Wl = Wh + (size_t)HID * 1024;

  const dim3 blk(256);
  for (int i = 0; i < 3; ++i) {
    const int D = in_sizes[i] / NROWS;
    int Kp = 256, ksh = 8;
    while (Kp < D) { Kp <<= 1; ksh++; }
    // encoder: pack limbs of x and W^T, then A = relu(x @ W + b)
    packAB_kernel<<<((NROWS + HID) << ksh) / 256, blk, 0, stream>>>(
        x[i], encW[i], Ah, Al, Wh, Wl, D, Kp, ksh);
    limbgemm_kernel<true, 1><<<512, blk, 0, stream>>>(Ah, Al, Wh, Wl,
                                                      enc_b + i * HID, A, Kp);
    // coalesced BN + fused rownorm/limb-emit
    bn_stats_kernel<<<64, blk, 0, stream>>>(A, ps, ps2);
    bn_finalize_kernel<<<1, blk, 0, stream>>>(ps, ps2, bn_g + i * HID, bn_b + i * HID,
                                              scale, shift);
    bn_rownorm_kernel<<<NROWS, blk, 0, stream>>>(A, scale, shift, FN, Ph, Fh, Fl);
    // stripe-free knn graph: tile-max pass -> tau -> compaction pass -> refine
    simtile_kernel<0><<<dim3(64, 64), dim3(512), 0, stream>>>(Ph, M, nullptr, nullptr, nullptr);
    tau_kernel<<<NROWS / 4, blk, 0, stream>>>(M, tauv, gcnt);
    simtile_kernel<1><<<dim3(64, 64), dim3(512), 0, stream>>>(Ph, nullptr, tauv, gcnt, gidx);
    refine_kernel<<<NROWS / 4, blk, 0, stream>>>(gcnt, gidx, FN, nidx, nval, dinv);
    // gc1: C = feat @ W1 (limb MFMA), h1 -> limbs via spmm epilogue
    packW_kernel<<<(HID * HID) / 256, blk, 0, stream>>>(gc1W + (size_t)i * HID * HID, Wh, Wl);
    limbgemm_kernel<false, 0><<<512, blk, 0, stream>>>(Fh, Fl, Wh, Wl, nullptr, C, HID);
    spmm_kernel<1><<<NROWS, blk, 0, stream>>>(C, nidx, nval, dinv, gc1b + i * HID,
                                              nullptr, Hh, Hl);
    // gc2
    packW_kernel<<<(HID * HID) / 256, blk, 0, stream>>>(gc2W + (size_t)i * HID * HID, Wh, Wl);
    limbgemm_kernel<false, 0><<<512, blk, 0, stream>>>(Hh, Hl, Wh, Wl, nullptr, C, HID);
    spmm_kernel<0><<<NROWS, blk, 0, stream>>>(C, nidx, nval, dinv, gc2b + i * HID,
                                              Bf, nullptr, nullptr);
    clf_kernel<<<(NROWS * NCLS + 255) / 256, blk, 0, stream>>>(Bf, clfW + (size_t)i * HID * NCLS,
                                                               clfb + i * NCLS,
                                                               logits + (size_t)i * NROWS * NCLS);
  }
  fuse_kernel<<<(NROWS * NCLS + 255) / 256, blk, 0, stream>>>(logits, attn, fused);
  head_kernel<<<NROWS, dim3(128), 0, stream>>>(fused, f1W, f1b, f2W, f2b, out);
}

// Round 12
// 971.421 us; speedup vs baseline: 1.4885x; 1.0545x over previous
//
#include <hip/hip_runtime.h>
#include <cfloat>
#include <cstdint>
#include <cstddef>

#define NROWS 8192
#define HID 256
#define NCLS 5
#define TOPK 10
#define CAP 256     // per-row candidate capacity (typ. ~20-60 used)
#define TM 128
#define TN 128
#define BK 32
#define BKS 64      // sim K-step

typedef __bf16 bf16x8 __attribute__((ext_vector_type(8)));
typedef float f32x4 __attribute__((ext_vector_type(4)));

__device__ inline ushort f2bf(float x) {
  unsigned u = __float_as_uint(x);
  unsigned r = (u + 0x7fffu + ((u >> 16) & 1u)) >> 16;  // RNE
  return (ushort)r;
}
__device__ inline float bf2f(ushort b) { return __uint_as_float(((unsigned)b) << 16); }

// async global->LDS 16B/lane; LDS dest is wave-uniform base + lane*16
__device__ __forceinline__ void load_lds16(const void* g, void* l) {
  __builtin_amdgcn_global_load_lds(
      (const __attribute__((address_space(1))) void*)g,
      (__attribute__((address_space(3))) void*)l, 16, 0, 0);
}

// ---------------------------------------------------------------------------
// Encoder pack: X rows (M x D fp32 -> hi/lo bf16 limb planes, K padded to Kp)
// and W (D x HID fp32, transposed -> HID x Kp limb planes).
// ---------------------------------------------------------------------------
__global__ __launch_bounds__(256) void packAB_kernel(const float* __restrict__ X,
    const float* __restrict__ W, ushort* __restrict__ Ah, ushort* __restrict__ Al,
    ushort* __restrict__ Bh, ushort* __restrict__ Bl, int D, int Kp, int ksh) {
  const int id = blockIdx.x * 256 + threadIdx.x;
  const int atotal = NROWS << ksh;
  if (id < atotal) {
    const int r = id >> ksh, k = id & (Kp - 1);
    const float x = (k < D) ? X[(size_t)r * D + k] : 0.f;
    const ushort h = f2bf(x);
    Ah[id] = h;
    Al[id] = f2bf(x - bf2f(h));
  } else {
    const int id2 = id - atotal;
    if (id2 < (HID << ksh)) {
      const int n = id2 >> ksh, k = id2 & (Kp - 1);
      const float x = (k < D) ? W[(size_t)k * HID + n] : 0.f;
      const ushort h = f2bf(x);
      Bh[id2] = h;
      Bl[id2] = f2bf(x - bf2f(h));
    }
  }
}

// ---------------------------------------------------------------------------
// GCN weight pack: W [HID x HID] -> transposed limb planes [HID x 256].
// ---------------------------------------------------------------------------
__global__ __launch_bounds__(256) void packW_kernel(const float* __restrict__ W,
    ushort* __restrict__ Bh, ushort* __restrict__ Bl) {
  const int id = blockIdx.x * 256 + threadIdx.x;  // 65536
  const int k = id >> 8, n = id & 255;            // coalesced read over n
  const float x = W[(size_t)k * HID + n];
  const ushort h = f2bf(x);
  Bh[(size_t)n * HID + k] = h;
  Bl[(size_t)n * HID + k] = f2bf(x - bf2f(h));
}

// ---------------------------------------------------------------------------
// 3-segment two-limb bf16 MFMA GEMM: C[NROWS x HID] = act(A @ B^T + bias).
// Segments hh + hl + lh (ll ~2^-18, dropped). 64x64 tile, 4 waves (2x2),
// XCD-swizzled 1-D grid for A-tile L2 reuse.
// ---------------------------------------------------------------------------
template<bool BIAS, int ACT>
__global__ __launch_bounds__(256) void limbgemm_kernel(const ushort* __restrict__ Ah,
    const ushort* __restrict__ Al, const ushort* __restrict__ Bh,
    const ushort* __restrict__ Bl, const float* __restrict__ bias,
    float* __restrict__ C, int Kp) {
  __shared__ ushort AsH[64 * BK], AsL[64 * BK], BsH[64 * BK], BsL[64 * BK];
  const int tid = threadIdx.x;
  const int wave = tid >> 6, lane = tid & 63;
  const int bid = blockIdx.x;
  const int xcd = bid & 7, slot = bid >> 3;
  const int bxi = slot & 3;
  const int byi = xcd * 16 + (slot >> 2);
  const int bm = byi * 64, bn = bxi * 64;
  const int wr = (wave >> 1) * 32, wc = (wave & 1) * 32;

  f32x4 acc[2][2];
  const f32x4 zero = {0.f, 0.f, 0.f, 0.f};
  acc[0][0] = zero; acc[0][1] = zero; acc[1][0] = zero; acc[1][1] = zero;

  const int r0 = tid >> 2, kl0 = (tid & 3) ^ ((r0 & 3) ^ ((r0 >> 2) & 1));
  const size_t aoff = (size_t)(bm + r0) * Kp + kl0 * 8;
  const size_t boff = (size_t)(bn + r0) * Kp + kl0 * 8;

  for (int k0 = 0; k0 < Kp; k0 += BK) {
    __syncthreads();
    load_lds16(Ah + aoff + k0, &AsH[tid * 8]);
    load_lds16(Al + aoff + k0, &AsL[tid * 8]);
    load_lds16(Bh + boff + k0, &BsH[tid * 8]);
    load_lds16(Bl + boff + k0, &BsL[tid * 8]);
    __syncthreads();
    bf16x8 ah[2], al[2], bh[2], bl[2];
    const int kg = lane >> 4;
    #pragma unroll
    for (int f = 0; f < 2; ++f) {
      const int m = wr + f * 16 + (lane & 15);
      const int sa = m * 4 + (kg ^ (m & 3) ^ ((m >> 2) & 1));
      ah[f] = *(const bf16x8*)&AsH[sa * 8];
      al[f] = *(const bf16x8*)&AsL[sa * 8];
      const int n = wc + f * 16 + (lane & 15);
      const int sb = n * 4 + (kg ^ (n & 3) ^ ((n >> 2) & 1));
      bh[f] = *(const bf16x8*)&BsH[sb * 8];
      bl[f] = *(const bf16x8*)&BsL[sb * 8];
    }
    #pragma unroll
    for (int fr = 0; fr < 2; ++fr)
      #pragma unroll
      for (int fc = 0; fc < 2; ++fc) {
        acc[fr][fc] = __builtin_amdgcn_mfma_f32_16x16x32_bf16(ah[fr], bh[fc], acc[fr][fc], 0, 0, 0);
        acc[fr][fc] = __builtin_amdgcn_mfma_f32_16x16x32_bf16(ah[fr], bl[fc], acc[fr][fc], 0, 0, 0);
        acc[fr][fc] = __builtin_amdgcn_mfma_f32_16x16x32_bf16(al[fr], bh[fc], acc[fr][fc], 0, 0, 0);
      }
  }
  const int cq = lane >> 4, cc = lane & 15;
  #pragma unroll
  for (int fr = 0; fr < 2; ++fr) {
    #pragma unroll
    for (int fc = 0; fc < 2; ++fc) {
      const int rb = bm + wr + fr * 16 + cq * 4;
      const int col = bn + wc + fc * 16 + cc;
      const float bb = BIAS ? bias[col] : 0.f;
      float* cp = C + (size_t)rb * HID + col;
      #pragma unroll
      for (int e = 0; e < 4; ++e) {
        float v = acc[fr][fc][e] + bb;
        if (ACT == 1) v = fmaxf(v, 0.f);
        cp[(size_t)e * HID] = v;
      }
    }
  }
}

// ---------------------------------------------------------------------------
// Coalesced BatchNorm, 3 stages.
// ---------------------------------------------------------------------------
__global__ __launch_bounds__(256) void bn_stats_kernel(const float* __restrict__ F,
    float* __restrict__ ps, float* __restrict__ ps2) {
  const int b = blockIdx.x, t = threadIdx.x;
  float s = 0.f, s2 = 0.f;
  const float* p = F + (size_t)b * 128 * HID + t;
  for (int r = 0; r < 128; ++r) {
    const float v = p[(size_t)r * HID];
    s += v; s2 += v * v;
  }
  ps[b * HID + t] = s;
  ps2[b * HID + t] = s2;
}

__global__ __launch_bounds__(256) void bn_finalize_kernel(const float* __restrict__ ps,
    const float* __restrict__ ps2, const float* __restrict__ g,
    const float* __restrict__ b, float* __restrict__ scale, float* __restrict__ shift) {
  const int t = threadIdx.x;
  float s = 0.f, s2 = 0.f;
  for (int i = 0; i < 64; ++i) { s += ps[i * HID + t]; s2 += ps2[i * HID + t]; }
  const float mu = s / (float)NROWS;
  const float var = s2 / (float)NROWS - mu * mu;
  const float rstd = rsqrtf(var + 1e-5f);
  const float sc = rstd * g[t];
  scale[t] = sc;
  shift[t] = b[t] - mu * sc;
}

// ---------------------------------------------------------------------------
// Fused bn-apply + L2 rownorm. Emits FN (fp32 fn), Ph (hi-limb fn),
// Fh/Fl (two-limb bn'd feat for gc1).
// ---------------------------------------------------------------------------
__global__ __launch_bounds__(256) void bn_rownorm_kernel(const float* __restrict__ F,
    const float* __restrict__ scale, const float* __restrict__ shift,
    float* __restrict__ FN, ushort* __restrict__ Ph,
    ushort* __restrict__ Fh, ushort* __restrict__ Fl) {
  const int r = blockIdx.x, t = threadIdx.x;
  const float f = F[(size_t)r * HID + t] * scale[t] + shift[t];
  __shared__ float sh[256];
  sh[t] = f * f;
  __syncthreads();
  for (int st = 128; st > 0; st >>= 1) {
    if (t < st) sh[t] += sh[t + st];
    __syncthreads();
  }
  const float inv = 1.0f / fmaxf(sqrtf(sh[0]), 1e-12f);
  const float fn = f * inv;
  const size_t o = (size_t)r * HID + t;
  FN[o] = fn;
  Ph[o] = f2bf(fn);
  const ushort h = f2bf(f);
  Fh[o] = h;
  Fl[o] = f2bf(f - bf2f(h));
}

// ---------------------------------------------------------------------------
// SYMMETRIC stripe-free sim: only upper-triangle tile pairs (by <= bx) are
// computed (2080 of 4096 blocks; sim=Ph@Ph^T is symmetric, so each off-diag
// tile serves BOTH its row band (row-part, as before) and its column band
// (col-part: per-column reduction of the same registers / appends the row
// index into the column's candidate list). ~2x less MFMA+staging work.
// 512 threads / 8 waves, wave = 32x64 sub-tile, BKS=64.
// PASS 0: per-row and per-col tile maxes -> M.  PASS 1: tau-compaction both
// directions. Sim values never touch HBM.
// ---------------------------------------------------------------------------
template<int PASS>
__global__ __launch_bounds__(512) void simtile_kernel(const ushort* __restrict__ P,
    float* __restrict__ M, const float* __restrict__ tauv,
    int* __restrict__ gcnt, int* __restrict__ gidx) {
  const int bx = blockIdx.x, by = blockIdx.y;
  if (by > bx) return;                 // lower-triangle blocks exit immediately
  const bool offdiag = (bx != by);
  __shared__ ushort As[TM * BKS];      // 16 KB
  __shared__ ushort Bs[TN * BKS];      // 16 KB
  __shared__ float Ml[2][TM];          // row-part partial maxes (2 wc halves)
  __shared__ float MlC[4][TN];         // col-part partial maxes (4 wr bands)
  __shared__ float taulA[TM];
  __shared__ float taulB[TN];
  const int tid = threadIdx.x;
  const int wave = tid >> 6, lane = tid & 63;
  const int bm = by * TM;
  const int bn = bx * TN;
  const int wr = (wave >> 1) * 32;     // 4 row-bands of 32
  const int wc = (wave & 1) * 64;      // 2 col-halves of 64

  if (PASS == 1) {
    if (tid < TM) taulA[tid] = tauv[bm + tid];
    else if (tid < TM + TN) taulB[tid - TM] = tauv[bn + (tid - TM)];
  }

  // staging: 1024 slots of 8 ushorts per tile; slot s: m=s>>3, kg=(s&7)^(m&7)
  const ushort* pa[2];
  const ushort* pb[2];
  #pragma unroll
  for (int j = 0; j < 2; ++j) {
    const int s = tid + j * 512;
    const int m = s >> 3;
    const int kg = (s & 7) ^ (m & 7);
    pa[j] = P + (size_t)(bm + m) * HID + kg * 8;
    pb[j] = P + (size_t)(bn + m) * HID + kg * 8;
  }

  f32x4 acc[2][4];
  const f32x4 zero = {0.f, 0.f, 0.f, 0.f};
  #pragma unroll
  for (int i = 0; i < 2; ++i)
    #pragma unroll
    for (int j = 0; j < 4; ++j) acc[i][j] = zero;

  for (int k0 = 0; k0 < HID; k0 += BKS) {
    __syncthreads();
    #pragma unroll
    for (int j = 0; j < 2; ++j) {
      load_lds16(pa[j] + k0, &As[(tid + j * 512) * 8]);
      load_lds16(pb[j] + k0, &Bs[(tid + j * 512) * 8]);
    }
    __syncthreads();
    #pragma unroll
    for (int h = 0; h < 2; ++h) {
      const int kgb = h * 4 + (lane >> 4);
      bf16x8 af[2], bf[4];
      #pragma unroll
      for (int f = 0; f < 2; ++f) {
        const int m = wr + f * 16 + (lane & 15);
        const int sa = m * 8 + (kgb ^ (m & 7));
        af[f] = *(const bf16x8*)&As[sa * 8];
      }
      #pragma unroll
      for (int f = 0; f < 4; ++f) {
        const int n = wc + f * 16 + (lane & 15);
        const int sb = n * 8 + (kgb ^ (n & 7));
        bf[f] = *(const bf16x8*)&Bs[sb * 8];
      }
      #pragma unroll
      for (int fr = 0; fr < 2; ++fr)
        #pragma unroll
        for (int fc = 0; fc < 4; ++fc)
          acc[fr][fc] = __builtin_amdgcn_mfma_f32_16x16x32_bf16(af[fr], bf[fc], acc[fr][fc], 0, 0, 0);
    }
  }

  const int cq = lane >> 4, cc = lane & 15;
  if (PASS == 0) {
    // ---- row-part: per-row max over this tile's 128 cols (self-excluded)
    #pragma unroll
    for (int fr = 0; fr < 2; ++fr) {
      #pragma unroll
      for (int e = 0; e < 4; ++e) {
        const int lrow = wr + fr * 16 + cq * 4 + e;
        const int grow = bm + lrow;
        float mx = -FLT_MAX;
        #pragma unroll
        for (int fc = 0; fc < 4; ++fc) {
          const int col = bn + wc + fc * 16 + cc;
          mx = fmaxf(mx, (col == grow) ? -FLT_MAX : acc[fr][fc][e]);
        }
        #pragma unroll
        for (int s = 1; s < 16; s <<= 1) mx = fmaxf(mx, __shfl_xor(mx, s));
        if (cc == 0) Ml[wave & 1][lrow] = mx;
      }
    }
    // ---- col-part (off-diag only): per-col max over this tile's 128 rows
    if (offdiag) {
      #pragma unroll
      for (int fc = 0; fc < 4; ++fc) {
        float mx = -FLT_MAX;
        #pragma unroll
        for (int fr = 0; fr < 2; ++fr)
          #pragma unroll
          for (int e = 0; e < 4; ++e) mx = fmaxf(mx, acc[fr][fc][e]);
        mx = fmaxf(mx, __shfl_xor(mx, 16));
        mx = fmaxf(mx, __shfl_xor(mx, 32));
        if (cq == 0) MlC[wave >> 1][wc + fc * 16 + cc] = mx;
      }
    }
    __syncthreads();
    if (tid < TM) M[(size_t)(bm + tid) * 64 + bx] = fmaxf(Ml[0][tid], Ml[1][tid]);
    if (offdiag && tid < TN) {
      const float mx = fmaxf(fmaxf(MlC[0][tid], MlC[1][tid]),
                             fmaxf(MlC[2][tid], MlC[3][tid]));
      M[(size_t)(bn + tid) * 64 + by] = mx;
    }
  } else {
    __syncthreads();  // taulA/taulB visible
    #pragma unroll
    for (int fr = 0; fr < 2; ++fr) {
      #pragma unroll
      for (int e = 0; e < 4; ++e) {
        const int lrow = wr + fr * 16 + cq * 4 + e;
        const int grow = bm + lrow;
        const float tA = taulA[lrow];
        #pragma unroll
        for (int fc = 0; fc < 4; ++fc) {
          const int lcol = wc + fc * 16 + cc;
          const int gcol = bn + lcol;
          const float v = acc[fr][fc][e];
          // row-part: candidate gcol for row grow
          if (gcol != grow && v >= tA) {
            const int pos = atomicAdd(&gcnt[grow], 1);
            if (pos < CAP) gidx[(size_t)grow * CAP + pos] = gcol;
          }
          // col-part (off-diag): candidate grow for row gcol (symmetry)
          if (offdiag && v >= taulB[lcol]) {
            const int pos = atomicAdd(&gcnt[gcol], 1);
            if (pos < CAP) gidx[(size_t)gcol * CAP + pos] = grow;
          }
        }
      }
    }
  }
}

// ---------------------------------------------------------------------------
// tau[row] = 16th largest of the 64 tile-maxes (valid top-16 lower bound:
// the top-16 tiles' maxes are 16 distinct non-self elements >= tau).
// Also zeroes gcnt (ws is re-poisoned before every launch).
// ---------------------------------------------------------------------------
__global__ __launch_bounds__(256) void tau_kernel(const float* __restrict__ M,
    float* __restrict__ tauv, int* __restrict__ gcnt) {
  const int wave = threadIdx.x >> 6, lane = threadIdx.x & 63;
  const int row = blockIdx.x * 4 + wave;
  float cur = M[(size_t)row * 64 + lane];
  float tau = cur;
  #pragma unroll
  for (int sel = 0; sel < 16; ++sel) {
    float bv = cur;
    int bl = lane;
    #pragma unroll
    for (int s = 1; s < 64; s <<= 1) {
      const float ov = __shfl_xor(bv, s);
      const int ol = __shfl_xor(bl, s);
      if (ov > bv || (ov == bv && ol < bl)) { bv = ov; bl = ol; }
    }
    tau = bv;
    if (lane == bl) cur = -FLT_MAX;
  }
  if (lane == 0) { tauv[row] = tau; gcnt[row] = 0; }
}

// ---------------------------------------------------------------------------
// Exact refinement: fp32 dots for all candidates, exact top-10, L1-normalize.
// One wave per row.
// ---------------------------------------------------------------------------
__global__ __launch_bounds__(256) void refine_kernel(const int* __restrict__ gcnt,
    const int* __restrict__ gidx, const float* __restrict__ FN,
    int* __restrict__ nidx, float* __restrict__ nval, float* __restrict__ dinv) {
  const int wave = threadIdx.x >> 6, lane = threadIdx.x & 63;
  const int row = blockIdx.x * 4 + wave;
  const int cnt = min(gcnt[row], CAP);
  __shared__ float fnrow[4][HID];
  __shared__ float ev[4][CAP];
  ((float4*)fnrow[wave])[lane] = ((const float4*)(FN + (size_t)row * HID))[lane];
  __syncthreads();
  const int c = lane >> 2, q4 = lane & 3;
  for (int b0 = 0; b0 < cnt; b0 += 16) {
    const int ci = b0 + c;
    const int cand = (ci < cnt) ? gidx[(size_t)row * CAP + ci] : 0;
    float s = 0.f;
    const float* fc = FN + (size_t)cand * HID + q4 * 64;
    const float* fr = fnrow[wave] + q4 * 64;
    #pragma unroll 8
    for (int k = 0; k < 64; ++k) s += fr[k] * fc[k];
    s += __shfl_xor(s, 1);
    s += __shfl_xor(s, 2);
    if (q4 == 0 && ci < cnt) ev[wave][ci] = s;
  }
  __syncthreads();
  float outv[TOPK];
  int outi[TOPK];
  float sum = 1.0f;  // diag contributes 1
  #pragma unroll
  for (int sel = 0; sel < TOPK; ++sel) {
    float bv = -FLT_MAX;
    int bp = 0;
    #pragma unroll
    for (int j = 0; j < 4; ++j) {
      const int p = lane + j * 64;
      if (p < cnt) {
        const float v = ev[wave][p];
        if (v > bv) { bv = v; bp = p; }
      }
    }
    #pragma unroll
    for (int s = 1; s < 64; s <<= 1) {
      const float ov = __shfl_xor(bv, s);
      const int op = __shfl_xor(bp, s);
      if (ov > bv || (ov == bv && op < bp)) { bv = ov; bp = op; }
    }
    outv[sel] = bv;
    outi[sel] = bp;
    sum += fabsf(bv);
    if (lane == 0) ev[wave][bp] = -FLT_MAX;
  }
  if (lane == 0) {
    const float inv = 1.0f / fmaxf(sum, 1e-12f);
    dinv[row] = inv;
    #pragma unroll
    for (int sel = 0; sel < TOPK; ++sel) {
      nval[row * TOPK + sel] = outv[sel] * inv;
      nidx[row * TOPK + sel] = gidx[(size_t)row * CAP + outi[sel]];
    }
  }
}

// ---------------------------------------------------------------------------
// Sparse adj (11 nnz/row) @ T + bias, leaky_relu(0.25).
// EMIT=0: write fp32 H. EMIT=1: write two-limb bf16 planes (next gemm's A).
// ---------------------------------------------------------------------------
template<int EMIT>
__global__ __launch_bounds__(256) void spmm_kernel(const float* __restrict__ T,
    const int* __restrict__ nidx, const float* __restrict__ nval,
    const float* __restrict__ dinv, const float* __restrict__ bias,
    float* __restrict__ H, ushort* __restrict__ Hh, ushort* __restrict__ Hl) {
  const int r = blockIdx.x, c = threadIdx.x;
  float acc = dinv[r] * T[(size_t)r * HID + c];
  #pragma unroll
  for (int n = 0; n < TOPK; ++n) {
    acc += nval[r * TOPK + n] * T[(size_t)nidx[r * TOPK + n] * HID + c];
  }
  acc += bias[c];
  const float v = acc >= 0.f ? acc : 0.25f * acc;
  const size_t o = (size_t)r * HID + c;
  if (EMIT == 0) {
    H[o] = v;
  } else {
    const ushort h = f2bf(v);
    Hh[o] = h;
    Hl[o] = f2bf(v - bf2f(h));
  }
}

__global__ __launch_bounds__(256) void clf_kernel(const float* __restrict__ H,
    const float* __restrict__ W, const float* __restrict__ b,
    float* __restrict__ L) {
  const int id = blockIdx.x * 256 + threadIdx.x;
  if (id >= NROWS * NCLS) return;
  const int r = id / NCLS, c = id % NCLS;
  float s = b[c];
  const float* hr = H + (size_t)r * HID;
  for (int k = 0; k < HID; ++k) s += hr[k] * W[k * NCLS + c];
  L[id] = s;
}

__global__ __launch_bounds__(256) void fuse_kernel(const float* __restrict__ L,
    const float* __restrict__ attn, float* __restrict__ fused) {
  const int id = blockIdx.x * 256 + threadIdx.x;
  if (id >= NROWS * NCLS) return;
  const float a0 = attn[0], a1 = attn[1], a2 = attn[2];
  const float m = fmaxf(a0, fmaxf(a1, a2));
  const float e0 = expf(a0 - m), e1 = expf(a1 - m), e2 = expf(a2 - m);
  const float inv = 1.0f / (e0 + e1 + e2);
  const float l0 = L[id];
  const float l1 = L[NROWS * NCLS + id];
  const float l2 = L[2 * NROWS * NCLS + id];
  const float s0 = 1.0f / (1.0f + expf(-l0));
  const float s1 = 1.0f / (1.0f + expf(-l1));
  const float s2 = 1.0f / (1.0f + expf(-l2));
  fused[id] = (e0 * s0 + e1 * s1 + e2 * s2) * inv;
}

__global__ __launch_bounds__(128) void head_kernel(const float* __restrict__ fused,
    const float* __restrict__ W1, const float* __restrict__ b1,
    const float* __restrict__ W2, const float* __restrict__ b2,
    float* __restrict__ out) {
  const int r = blockIdx.x, t = threadIdx.x;
  __shared__ float f[NCLS];
  __shared__ float hh[128];
  if (t < NCLS) f[t] = fused[r * NCLS + t];
  __syncthreads();
  float s = b1[t];
  #pragma unroll
  for (int k = 0; k < NCLS; ++k) s += f[k] * W1[k * 128 + t];
  hh[t] = s >= 0.f ? s : 0.25f * s;
  __syncthreads();
  if (t < NCLS) {
    float o = b2[t];
    for (int k = 0; k < 128; ++k) o += hh[k] * W2[k * NCLS + t];
    out[r * NCLS + t] = o;
  }
}

// ---------------------------------------------------------------------------
extern "C" void kernel_launch(void* const* d_in, const int* in_sizes, int n_in,
                              void* d_out, int out_size, void* d_ws, size_t ws_size,
                              hipStream_t stream) {
  const float* x[3]    = {(const float*)d_in[0], (const float*)d_in[1], (const float*)d_in[2]};
  const float* encW[3] = {(const float*)d_in[3], (const float*)d_in[4], (const float*)d_in[5]};
  const float* enc_b = (const float*)d_in[6];
  const float* bn_g  = (const float*)d_in[7];
  const float* bn_b  = (const float*)d_in[8];
  const float* gc1W  = (const float*)d_in[9];
  const float* gc1b  = (const float*)d_in[10];
  const float* gc2W  = (const float*)d_in[11];
  const float* gc2b  = (const float*)d_in[12];
  const float* clfW  = (const float*)d_in[13];
  const float* clfb  = (const float*)d_in[14];
  const float* attn  = (const float*)d_in[15];
  const float* f1W   = (const float*)d_in[16];
  const float* f1b   = (const float*)d_in[17];
  const float* f2W   = (const float*)d_in[18];
  const float* f2b   = (const float*)d_in[19];
  float* out = (float*)d_out;

  // Workspace layout
  const size_t NH = (size_t)NROWS * HID;
  float* ws = (float*)d_ws;
  float* FN = ws;                                  // fp32 fn
  float* A  = FN + NH;                             // encoder out (pre-bn)
  float* C  = A + NH;                              // gemm temp
  float* Bf = C + NH;                              // h2 fp32
  int*   nidx = (int*)(Bf + NH);
  float* nval = (float*)(nidx + (size_t)NROWS * TOPK);
  float* dinv = nval + (size_t)NROWS * TOPK;
  float* logits = dinv + NROWS;
  float* fused = logits + (size_t)3 * NROWS * NCLS;
  float* ps    = fused + (size_t)NROWS * NCLS;     // 64*256
  float* ps2   = ps + 64 * HID;
  float* scale = ps2 + 64 * HID;
  float* shift = scale + HID;
  float* M     = shift + HID;                      // 8192*64 tile maxes
  float* tauv  = M + (size_t)NROWS * 64;           // 8192
  int*   gcnt  = (int*)(tauv + NROWS);             // 8192
  int*   gidx  = gcnt + NROWS;                     // 8192*CAP
  ushort* Ph = (ushort*)(gidx + (size_t)NROWS * CAP);  // hi-limb fn
  ushort* Fh = Ph + NH;                            // gc1 A limbs
  ushort* Fl = Fh + NH;
  ushort* Hh = Fl + NH;                            // gc2 A limbs
  ushort* Hl = Hh + NH;
  ushort* Ah = Hl + NH;                            // encoder A limbs (Kp<=1024)
  ushort* Al = Ah + (size_t)NROWS * 1024;
  ushort* Wh = Al + (size_t)NROWS * 1024;          // B limbs (HID x Kp<=1024)
  ushort* Wl = Wh + (size_t)HID * 1024;

  const dim3 blk(256);
  for (int i = 0; i < 3; ++i) {
    const int D = in_sizes[i] / NROWS;
    int Kp = 256, ksh = 8;
    while (Kp < D) { Kp <<= 1; ksh++; }
    // encoder: pack limbs of x and W^T, then A = relu(x @ W + b)
    packAB_kernel<<<((NROWS + HID) << ksh) / 256, blk, 0, stream>>>(
        x[i], encW[i], Ah, Al, Wh, Wl, D, Kp, ksh);
    limbgemm_kernel<true, 1><<<512, blk, 0, stream>>>(Ah, Al, Wh, Wl,
                                                      enc_b + i * HID, A, Kp);
    // coalesced BN + fused rownorm/limb-emit
    bn_stats_kernel<<<64, blk, 0, stream>>>(A, ps, ps2);
    bn_finalize_kernel<<<1, blk, 0, stream>>>(ps, ps2, bn_g + i * HID, bn_b + i * HID,
                                              scale, shift);
    bn_rownorm_kernel<<<NROWS, blk, 0, stream>>>(A, scale, shift, FN, Ph, Fh, Fl);
    // symmetric stripe-free knn graph: tile-max -> tau -> compaction -> refine
    simtile_kernel<0><<<dim3(64, 64), dim3(512), 0, stream>>>(Ph, M, nullptr, nullptr, nullptr);
    tau_kernel<<<NROWS / 4, blk, 0, stream>>>(M, tauv, gcnt);
    simtile_kernel<1><<<dim3(64, 64), dim3(512), 0, stream>>>(Ph, nullptr, tauv, gcnt, gidx);
    refine_kernel<<<NROWS / 4, blk, 0, stream>>>(gcnt, gidx, FN, nidx, nval, dinv);
    // gc1: C = feat @ W1 (limb MFMA), h1 -> limbs via spmm epilogue
    packW_kernel<<<(HID * HID) / 256, blk, 0, stream>>>(gc1W + (size_t)i * HID * HID, Wh, Wl);
    limbgemm_kernel<false, 0><<<512, blk, 0, stream>>>(Fh, Fl, Wh, Wl, nullptr, C, HID);
    spmm_kernel<1><<<NROWS, blk, 0, stream>>>(C, nidx, nval, dinv, gc1b + i * HID,
                                              nullptr, Hh, Hl);
    // gc2
    packW_kernel<<<(HID * HID) / 256, blk, 0, stream>>>(gc2W + (size_t)i * HID * HID, Wh, Wl);
    limbgemm_kernel<false, 0><<<512, blk, 0, stream>>>(Hh, Hl, Wh, Wl, nullptr, C, HID);
    spmm_kernel<0><<<NROWS, blk, 0, stream>>>(C, nidx, nval, dinv, gc2b + i * HID,
                                              Bf, nullptr, nullptr);
    clf_kernel<<<(NROWS * NCLS + 255) / 256, blk, 0, stream>>>(Bf, clfW + (size_t)i * HID * NCLS,
                                                               clfb + i * NCLS,
                                                               logits + (size_t)i * NROWS * NCLS);
  }
  fuse_kernel<<<(NROWS * NCLS + 255) / 256, blk, 0, stream>>>(logits, attn, fused);
  head_kernel<<<NROWS, dim3(128), 0, stream>>>(fused, f1W, f1b, f2W, f2b, out);
}

// Round 14
// 838.983 us; speedup vs baseline: 1.7235x; 1.1579x over previous
//
#include <hip/hip_runtime.h>
#include <cfloat>
#include <cstdint>
#include <cstddef>

#define NROWS 8192
#define HID 256
#define NCLS 5
#define TOPK 10
#define CAP 256     // per-row candidate capacity (typ. ~20-60 used)
#define TM 128
#define TN 128
#define BK 32
#define BKS 64      // sim K-step

typedef __bf16 bf16x8 __attribute__((ext_vector_type(8)));
typedef float f32x4 __attribute__((ext_vector_type(4)));

__device__ inline ushort f2bf(float x) {
  unsigned u = __float_as_uint(x);
  unsigned r = (u + 0x7fffu + ((u >> 16) & 1u)) >> 16;  // RNE
  return (ushort)r;
}
__device__ inline float bf2f(ushort b) { return __uint_as_float(((unsigned)b) << 16); }

// async global->LDS 16B/lane; LDS dest is wave-uniform base + lane*16
__device__ __forceinline__ void load_lds16(const void* g, void* l) {
  __builtin_amdgcn_global_load_lds(
      (const __attribute__((address_space(1))) void*)g,
      (__attribute__((address_space(3))) void*)l, 16, 0, 0);
}

// ---------------------------------------------------------------------------
// Batched encoder pack (z = modality): X -> hi/lo limb planes (COMPACT per-z
// row stride Kp[z], zero-padded past D), W -> transposed [HID x Kp[z]] planes.
// ---------------------------------------------------------------------------
__global__ __launch_bounds__(256) void packAB_kernel(const float* __restrict__ X0,
    const float* __restrict__ X1, const float* __restrict__ X2,
    const float* __restrict__ W0, const float* __restrict__ W1,
    const float* __restrict__ W2, ushort* __restrict__ Ah, ushort* __restrict__ Al,
    ushort* __restrict__ Bh, ushort* __restrict__ Bl,
    int D0, int D1, int D2, int Kp0, int Kp1, int Kp2,
    size_t aOff0, size_t aOff1, size_t aOff2,
    size_t wOff0, size_t wOff1, size_t wOff2) {
  const int z = blockIdx.y;
  const float* X = (z == 0) ? X0 : (z == 1) ? X1 : X2;
  const float* W = (z == 0) ? W0 : (z == 1) ? W1 : W2;
  const int D = (z == 0) ? D0 : (z == 1) ? D1 : D2;
  const int Kp = (z == 0) ? Kp0 : (z == 1) ? Kp1 : Kp2;
  const size_t aOff = (z == 0) ? aOff0 : (z == 1) ? aOff1 : aOff2;
  const size_t wOff = (z == 0) ? wOff0 : (z == 1) ? wOff1 : wOff2;
  const int ksh = 31 - __clz(Kp);
  const int id = blockIdx.x * 256 + threadIdx.x;
  const int atotal = NROWS << ksh;
  if (id >= atotal + (HID << ksh)) return;
  if (id < atotal) {
    const int k = id & (Kp - 1);
    const int r = id >> ksh;
    const float x = (k < D) ? X[(size_t)r * D + k] : 0.f;
    const ushort h = f2bf(x);
    Ah[aOff + id] = h;
    Al[aOff + id] = f2bf(x - bf2f(h));
  } else {
    const int id2 = id - atotal;
    const int k = id2 & (Kp - 1);
    const int n = id2 >> ksh;
    const float x = (k < D) ? W[(size_t)k * HID + n] : 0.f;
    const ushort h = f2bf(x);
    Bh[wOff + id2] = h;
    Bl[wOff + id2] = f2bf(x - bf2f(h));
  }
}

// ---------------------------------------------------------------------------
// Batched GCN weight pack: W[z] [HID x HID] -> transposed limb planes.
// ---------------------------------------------------------------------------
__global__ __launch_bounds__(256) void packW_kernel(const float* __restrict__ W,
    ushort* __restrict__ Bh, ushort* __restrict__ Bl) {
  const int z = blockIdx.y;
  const int id = blockIdx.x * 256 + threadIdx.x;  // 65536 per z
  const int k = id >> 8, n = id & 255;
  const size_t wz = (size_t)z * HID * HID;
  const float x = W[wz + (size_t)k * HID + n];
  const ushort h = f2bf(x);
  Bh[wz + (size_t)n * HID + k] = h;
  Bl[wz + (size_t)n * HID + k] = f2bf(x - bf2f(h));
}

// ---------------------------------------------------------------------------
// Batched 3-segment two-limb bf16 MFMA GEMM: C[z] = act(A[z] @ B[z]^T + bias).
// Planes are compact: row stride == Kp[z]; per-z base offsets aOff/bOff.
// 64x64 tile, 4 waves, XCD-swizzled blockIdx.x for A-tile L2 reuse.
// ---------------------------------------------------------------------------
template<bool BIAS, int ACT>
__global__ __launch_bounds__(256) void limbgemm_kernel(const ushort* __restrict__ Ah,
    const ushort* __restrict__ Al, const ushort* __restrict__ Bh,
    const ushort* __restrict__ Bl, const float* __restrict__ bias,
    float* __restrict__ C, int Kp0, int Kp1, int Kp2,
    size_t aOff0, size_t aOff1, size_t aOff2,
    size_t bOff0, size_t bOff1, size_t bOff2) {
  __shared__ ushort AsH[64 * BK], AsL[64 * BK], BsH[64 * BK], BsL[64 * BK];
  const int z = blockIdx.y;
  const int Kp = (z == 0) ? Kp0 : (z == 1) ? Kp1 : Kp2;
  const size_t aO = (z == 0) ? aOff0 : (z == 1) ? aOff1 : aOff2;
  const size_t bO = (z == 0) ? bOff0 : (z == 1) ? bOff1 : bOff2;
  Ah += aO; Al += aO; Bh += bO; Bl += bO;
  C += (size_t)z * NROWS * HID;
  const int tid = threadIdx.x;
  const int wave = tid >> 6, lane = tid & 63;
  const int bid = blockIdx.x;
  const int xcd = bid & 7, slot = bid >> 3;
  const int bxi = slot & 3;
  const int byi = xcd * 16 + (slot >> 2);
  const int bm = byi * 64, bn = bxi * 64;
  const int wr = (wave >> 1) * 32, wc = (wave & 1) * 32;

  f32x4 acc[2][2];
  const f32x4 zero = {0.f, 0.f, 0.f, 0.f};
  acc[0][0] = zero; acc[0][1] = zero; acc[1][0] = zero; acc[1][1] = zero;

  const int r0 = tid >> 2, kl0 = (tid & 3) ^ ((r0 & 3) ^ ((r0 >> 2) & 1));
  const size_t aoff = (size_t)(bm + r0) * Kp + kl0 * 8;
  const size_t boff = (size_t)(bn + r0) * Kp + kl0 * 8;

  for (int k0 = 0; k0 < Kp; k0 += BK) {
    __syncthreads();
    load_lds16(Ah + aoff + k0, &AsH[tid * 8]);
    load_lds16(Al + aoff + k0, &AsL[tid * 8]);
    load_lds16(Bh + boff + k0, &BsH[tid * 8]);
    load_lds16(Bl + boff + k0, &BsL[tid * 8]);
    __syncthreads();
    bf16x8 ah[2], al[2], bh[2], bl[2];
    const int kg = lane >> 4;
    #pragma unroll
    for (int f = 0; f < 2; ++f) {
      const int m = wr + f * 16 + (lane & 15);
      const int sa = m * 4 + (kg ^ (m & 3) ^ ((m >> 2) & 1));
      ah[f] = *(const bf16x8*)&AsH[sa * 8];
      al[f] = *(const bf16x8*)&AsL[sa * 8];
      const int n = wc + f * 16 + (lane & 15);
      const int sb = n * 4 + (kg ^ (n & 3) ^ ((n >> 2) & 1));
      bh[f] = *(const bf16x8*)&BsH[sb * 8];
      bl[f] = *(const bf16x8*)&BsL[sb * 8];
    }
    #pragma unroll
    for (int fr = 0; fr < 2; ++fr)
      #pragma unroll
      for (int fc = 0; fc < 2; ++fc) {
        acc[fr][fc] = __builtin_amdgcn_mfma_f32_16x16x32_bf16(ah[fr], bh[fc], acc[fr][fc], 0, 0, 0);
        acc[fr][fc] = __builtin_amdgcn_mfma_f32_16x16x32_bf16(ah[fr], bl[fc], acc[fr][fc], 0, 0, 0);
        acc[fr][fc] = __builtin_amdgcn_mfma_f32_16x16x32_bf16(al[fr], bh[fc], acc[fr][fc], 0, 0, 0);
      }
  }
  const int cq = lane >> 4, cc = lane & 15;
  #pragma unroll
  for (int fr = 0; fr < 2; ++fr) {
    #pragma unroll
    for (int fc = 0; fc < 2; ++fc) {
      const int rb = bm + wr + fr * 16 + cq * 4;
      const int col = bn + wc + fc * 16 + cc;
      const float bb = BIAS ? bias[z * HID + col] : 0.f;
      float* cp = C + (size_t)rb * HID + col;
      #pragma unroll
      for (int e = 0; e < 4; ++e) {
        float v = acc[fr][fc][e] + bb;
        if (ACT == 1) v = fmaxf(v, 0.f);
        cp[(size_t)e * HID] = v;
      }
    }
  }
}

// ---------------------------------------------------------------------------
// Batched coalesced BatchNorm, 3 stages.
// ---------------------------------------------------------------------------
__global__ __launch_bounds__(256) void bn_stats_kernel(const float* __restrict__ F,
    float* __restrict__ ps, float* __restrict__ ps2) {
  const int z = blockIdx.y;
  const int b = blockIdx.x, t = threadIdx.x;
  float s = 0.f, s2 = 0.f;
  const float* p = F + (size_t)z * NROWS * HID + (size_t)b * 128 * HID + t;
  for (int r = 0; r < 128; ++r) {
    const float v = p[(size_t)r * HID];
    s += v; s2 += v * v;
  }
  ps[(size_t)z * 64 * HID + b * HID + t] = s;
  ps2[(size_t)z * 64 * HID + b * HID + t] = s2;
}

__global__ __launch_bounds__(256) void bn_finalize_kernel(const float* __restrict__ ps,
    const float* __restrict__ ps2, const float* __restrict__ g,
    const float* __restrict__ b, float* __restrict__ scale, float* __restrict__ shift) {
  const int z = blockIdx.x;
  const int t = threadIdx.x;
  float s = 0.f, s2 = 0.f;
  for (int i = 0; i < 64; ++i) {
    s += ps[(size_t)z * 64 * HID + i * HID + t];
    s2 += ps2[(size_t)z * 64 * HID + i * HID + t];
  }
  const float mu = s / (float)NROWS;
  const float var = s2 / (float)NROWS - mu * mu;
  const float rstd = rsqrtf(var + 1e-5f);
  const float sc = rstd * g[z * HID + t];
  scale[z * HID + t] = sc;
  shift[z * HID + t] = b[z * HID + t] - mu * sc;
}

// ---------------------------------------------------------------------------
// Batched fused bn-apply + L2 rownorm. Emits FN, Ph (hi-limb fn), Fh/Fl.
// ---------------------------------------------------------------------------
__global__ __launch_bounds__(256) void bn_rownorm_kernel(const float* __restrict__ F,
    const float* __restrict__ scale, const float* __restrict__ shift,
    float* __restrict__ FN, ushort* __restrict__ Ph,
    ushort* __restrict__ Fh, ushort* __restrict__ Fl) {
  const int z = blockIdx.y;
  const int r = blockIdx.x, t = threadIdx.x;
  const size_t zb = (size_t)z * NROWS * HID;
  const float f = F[zb + (size_t)r * HID + t] * scale[z * HID + t] + shift[z * HID + t];
  __shared__ float sh[256];
  sh[t] = f * f;
  __syncthreads();
  for (int st = 128; st > 0; st >>= 1) {
    if (t < st) sh[t] += sh[t + st];
    __syncthreads();
  }
  const float inv = 1.0f / fmaxf(sqrtf(sh[0]), 1e-12f);
  const float fn = f * inv;
  const size_t o = zb + (size_t)r * HID + t;
  FN[o] = fn;
  Ph[o] = f2bf(fn);
  const ushort h = f2bf(f);
  Fh[o] = h;
  Fl[o] = f2bf(f - bf2f(h));
}

// ---------------------------------------------------------------------------
// Batched SYMMETRIC stripe-free sim (z = blockIdx.z): upper-triangle tile
// pairs only; off-diag tiles serve row band AND column band from registers.
// PASS 0: per-row/per-col tile maxes -> M. PASS 1: tau-compaction both dirs.
// ---------------------------------------------------------------------------
template<int PASS>
__global__ __launch_bounds__(512) void simtile_kernel(const ushort* __restrict__ P,
    float* __restrict__ M, const float* __restrict__ tauv,
    int* __restrict__ gcnt, int* __restrict__ gidx) {
  const int bx = blockIdx.x, by = blockIdx.y;
  if (by > bx) return;
  const int z = blockIdx.z;
  P += (size_t)z * NROWS * HID;
  if (PASS == 0) M += (size_t)z * NROWS * 64;
  else {
    tauv += (size_t)z * NROWS;
    gcnt += (size_t)z * NROWS;
    gidx += (size_t)z * NROWS * CAP;
  }
  const bool offdiag = (bx != by);
  __shared__ ushort As[TM * BKS];
  __shared__ ushort Bs[TN * BKS];
  __shared__ float Ml[2][TM];
  __shared__ float MlC[4][TN];
  __shared__ float taulA[TM];
  __shared__ float taulB[TN];
  const int tid = threadIdx.x;
  const int wave = tid >> 6, lane = tid & 63;
  const int bm = by * TM;
  const int bn = bx * TN;
  const int wr = (wave >> 1) * 32;
  const int wc = (wave & 1) * 64;

  if (PASS == 1) {
    if (tid < TM) taulA[tid] = tauv[bm + tid];
    else if (tid < TM + TN) taulB[tid - TM] = tauv[bn + (tid - TM)];
  }

  const ushort* pa[2];
  const ushort* pb[2];
  #pragma unroll
  for (int j = 0; j < 2; ++j) {
    const int s = tid + j * 512;
    const int m = s >> 3;
    const int kg = (s & 7) ^ (m & 7);
    pa[j] = P + (size_t)(bm + m) * HID + kg * 8;
    pb[j] = P + (size_t)(bn + m) * HID + kg * 8;
  }

  f32x4 acc[2][4];
  const f32x4 zero = {0.f, 0.f, 0.f, 0.f};
  #pragma unroll
  for (int i = 0; i < 2; ++i)
    #pragma unroll
    for (int j = 0; j < 4; ++j) acc[i][j] = zero;

  for (int k0 = 0; k0 < HID; k0 += BKS) {
    __syncthreads();
    #pragma unroll
    for (int j = 0; j < 2; ++j) {
      load_lds16(pa[j] + k0, &As[(tid + j * 512) * 8]);
      load_lds16(pb[j] + k0, &Bs[(tid + j * 512) * 8]);
    }
    __syncthreads();
    #pragma unroll
    for (int h = 0; h < 2; ++h) {
      const int kgb = h * 4 + (lane >> 4);
      bf16x8 af[2], bf[4];
      #pragma unroll
      for (int f = 0; f < 2; ++f) {
        const int m = wr + f * 16 + (lane & 15);
        const int sa = m * 8 + (kgb ^ (m & 7));
        af[f] = *(const bf16x8*)&As[sa * 8];
      }
      #pragma unroll
      for (int f = 0; f < 4; ++f) {
        const int n = wc + f * 16 + (lane & 15);
        const int sb = n * 8 + (kgb ^ (n & 7));
        bf[f] = *(const bf16x8*)&Bs[sb * 8];
      }
      #pragma unroll
      for (int fr = 0; fr < 2; ++fr)
        #pragma unroll
        for (int fc = 0; fc < 4; ++fc)
          acc[fr][fc] = __builtin_amdgcn_mfma_f32_16x16x32_bf16(af[fr], bf[fc], acc[fr][fc], 0, 0, 0);
    }
  }

  const int cq = lane >> 4, cc = lane & 15;
  if (PASS == 0) {
    #pragma unroll
    for (int fr = 0; fr < 2; ++fr) {
      #pragma unroll
      for (int e = 0; e < 4; ++e) {
        const int lrow = wr + fr * 16 + cq * 4 + e;
        const int grow = bm + lrow;
        float mx = -FLT_MAX;
        #pragma unroll
        for (int fc = 0; fc < 4; ++fc) {
          const int col = bn + wc + fc * 16 + cc;
          mx = fmaxf(mx, (col == grow) ? -FLT_MAX : acc[fr][fc][e]);
        }
        #pragma unroll
        for (int s = 1; s < 16; s <<= 1) mx = fmaxf(mx, __shfl_xor(mx, s));
        if (cc == 0) Ml[wave & 1][lrow] = mx;
      }
    }
    if (offdiag) {
      #pragma unroll
      for (int fc = 0; fc < 4; ++fc) {
        float mx = -FLT_MAX;
        #pragma unroll
        for (int fr = 0; fr < 2; ++fr)
          #pragma unroll
          for (int e = 0; e < 4; ++e) mx = fmaxf(mx, acc[fr][fc][e]);
        mx = fmaxf(mx, __shfl_xor(mx, 16));
        mx = fmaxf(mx, __shfl_xor(mx, 32));
        if (cq == 0) MlC[wave >> 1][wc + fc * 16 + cc] = mx;
      }
    }
    __syncthreads();
    if (tid < TM) M[(size_t)(bm + tid) * 64 + bx] = fmaxf(Ml[0][tid], Ml[1][tid]);
    if (offdiag && tid < TN) {
      const float mx = fmaxf(fmaxf(MlC[0][tid], MlC[1][tid]),
                             fmaxf(MlC[2][tid], MlC[3][tid]));
      M[(size_t)(bn + tid) * 64 + by] = mx;
    }
  } else {
    __syncthreads();
    #pragma unroll
    for (int fr = 0; fr < 2; ++fr) {
      #pragma unroll
      for (int e = 0; e < 4; ++e) {
        const int lrow = wr + fr * 16 + cq * 4 + e;
        const int grow = bm + lrow;
        const float tA = taulA[lrow];
        #pragma unroll
        for (int fc = 0; fc < 4; ++fc) {
          const int lcol = wc + fc * 16 + cc;
          const int gcol = bn + lcol;
          const float v = acc[fr][fc][e];
          if (gcol != grow && v >= tA) {
            const int pos = atomicAdd(&gcnt[grow], 1);
            if (pos < CAP) gidx[(size_t)grow * CAP + pos] = gcol;
          }
          if (offdiag && v >= taulB[lcol]) {
            const int pos = atomicAdd(&gcnt[gcol], 1);
            if (pos < CAP) gidx[(size_t)gcol * CAP + pos] = grow;
          }
        }
      }
    }
  }
}

// ---------------------------------------------------------------------------
// Batched tau: tau[row] = 16th largest of 64 tile-maxes; zeroes gcnt.
// ---------------------------------------------------------------------------
__global__ __launch_bounds__(256) void tau_kernel(const float* __restrict__ M,
    float* __restrict__ tauv, int* __restrict__ gcnt) {
  const int z = blockIdx.y;
  const int wave = threadIdx.x >> 6, lane = threadIdx.x & 63;
  const int row = blockIdx.x * 4 + wave;
  float cur = M[(size_t)z * NROWS * 64 + (size_t)row * 64 + lane];
  float tau = cur;
  #pragma unroll
  for (int sel = 0; sel < 16; ++sel) {
    float bv = cur;
    int bl = lane;
    #pragma unroll
    for (int s = 1; s < 64; s <<= 1) {
      const float ov = __shfl_xor(bv, s);
      const int ol = __shfl_xor(bl, s);
      if (ov > bv || (ov == bv && ol < bl)) { bv = ov; bl = ol; }
    }
    tau = bv;
    if (lane == bl) cur = -FLT_MAX;
  }
  if (lane == 0) {
    tauv[(size_t)z * NROWS + row] = tau;
    gcnt[(size_t)z * NROWS + row] = 0;
  }
}

// ---------------------------------------------------------------------------
// Batched exact refinement: fp32 dots for all candidates, exact top-10.
// ---------------------------------------------------------------------------
__global__ __launch_bounds__(256) void refine_kernel(const int* __restrict__ gcnt,
    const int* __restrict__ gidx, const float* __restrict__ FN,
    int* __restrict__ nidx, float* __restrict__ nval, float* __restrict__ dinv) {
  const int z = blockIdx.y;
  gcnt += (size_t)z * NROWS;
  gidx += (size_t)z * NROWS * CAP;
  FN += (size_t)z * NROWS * HID;
  nidx += (size_t)z * NROWS * TOPK;
  nval += (size_t)z * NROWS * TOPK;
  dinv += (size_t)z * NROWS;
  const int wave = threadIdx.x >> 6, lane = threadIdx.x & 63;
  const int row = blockIdx.x * 4 + wave;
  const int cnt = min(gcnt[row], CAP);
  __shared__ float fnrow[4][HID];
  __shared__ float ev[4][CAP];
  ((float4*)fnrow[wave])[lane] = ((const float4*)(FN + (size_t)row * HID))[lane];
  __syncthreads();
  const int c = lane >> 2, q4 = lane & 3;
  for (int b0 = 0; b0 < cnt; b0 += 16) {
    const int ci = b0 + c;
    const int cand = (ci < cnt) ? gidx[(size_t)row * CAP + ci] : 0;
    float s = 0.f;
    const float* fc = FN + (size_t)cand * HID + q4 * 64;
    const float* fr = fnrow[wave] + q4 * 64;
    #pragma unroll 8
    for (int k = 0; k < 64; ++k) s += fr[k] * fc[k];
    s += __shfl_xor(s, 1);
    s += __shfl_xor(s, 2);
    if (q4 == 0 && ci < cnt) ev[wave][ci] = s;
  }
  __syncthreads();
  float outv[TOPK];
  int outi[TOPK];
  float sum = 1.0f;  // diag contributes 1
  #pragma unroll
  for (int sel = 0; sel < TOPK; ++sel) {
    float bv = -FLT_MAX;
    int bp = 0;
    #pragma unroll
    for (int j = 0; j < 4; ++j) {
      const int p = lane + j * 64;
      if (p < cnt) {
        const float v = ev[wave][p];
        if (v > bv) { bv = v; bp = p; }
      }
    }
    #pragma unroll
    for (int s = 1; s < 64; s <<= 1) {
      const float ov = __shfl_xor(bv, s);
      const int op = __shfl_xor(bp, s);
      if (ov > bv || (ov == bv && op < bp)) { bv = ov; bp = op; }
    }
    outv[sel] = bv;
    outi[sel] = bp;
    sum += fabsf(bv);
    if (lane == 0) ev[wave][bp] = -FLT_MAX;
  }
  if (lane == 0) {
    const float inv = 1.0f / fmaxf(sum, 1e-12f);
    dinv[row] = inv;
    #pragma unroll
    for (int sel = 0; sel < TOPK; ++sel) {
      nval[row * TOPK + sel] = outv[sel] * inv;
      nidx[row * TOPK + sel] = gidx[(size_t)row * CAP + outi[sel]];
    }
  }
}

// ---------------------------------------------------------------------------
// Batched sparse adj (11 nnz/row) @ T + bias, leaky_relu(0.25).
// EMIT=0: write fp32 H. EMIT=1: write two-limb bf16 planes.
// ---------------------------------------------------------------------------
template<int EMIT>
__global__ __launch_bounds__(256) void spmm_kernel(const float* __restrict__ T,
    const int* __restrict__ nidx, const float* __restrict__ nval,
    const float* __restrict__ dinv, const float* __restrict__ bias,
    float* __restrict__ H, ushort* __restrict__ Hh, ushort* __restrict__ Hl) {
  const int z = blockIdx.y;
  const size_t zb = (size_t)z * NROWS * HID;
  T += zb;
  nidx += (size_t)z * NROWS * TOPK;
  nval += (size_t)z * NROWS * TOPK;
  dinv += (size_t)z * NROWS;
  const int r = blockIdx.x, c = threadIdx.x;
  float acc = dinv[r] * T[(size_t)r * HID + c];
  #pragma unroll
  for (int n = 0; n < TOPK; ++n) {
    acc += nval[r * TOPK + n] * T[(size_t)nidx[r * TOPK + n] * HID + c];
  }
  acc += bias[z * HID + c];
  const float v = acc >= 0.f ? acc : 0.25f * acc;
  const size_t o = zb + (size_t)r * HID + c;
  if (EMIT == 0) {
    H[o] = v;
  } else {
    const ushort h = f2bf(v);
    Hh[o] = h;
    Hl[o] = f2bf(v - bf2f(h));
  }
}

__global__ __launch_bounds__(256) void clf_kernel(const float* __restrict__ H,
    const float* __restrict__ W, const float* __restrict__ b,
    float* __restrict__ L) {
  const int z = blockIdx.y;
  const int id = blockIdx.x * 256 + threadIdx.x;
  if (id >= NROWS * NCLS) return;
  const int r = id / NCLS, c = id % NCLS;
  float s = b[z * NCLS + c];
  const float* hr = H + (size_t)z * NROWS * HID + (size_t)r * HID;
  const float* wz = W + (size_t)z * HID * NCLS;
  for (int k = 0; k < HID; ++k) s += hr[k] * wz[k * NCLS + c];
  L[(size_t)z * NROWS * NCLS + id] = s;
}

__global__ __launch_bounds__(256) void fuse_kernel(const float* __restrict__ L,
    const float* __restrict__ attn, float* __restrict__ fused) {
  const int id = blockIdx.x * 256 + threadIdx.x;
  if (id >= NROWS * NCLS) return;
  const float a0 = attn[0], a1 = attn[1], a2 = attn[2];
  const float m = fmaxf(a0, fmaxf(a1, a2));
  const float e0 = expf(a0 - m), e1 = expf(a1 - m), e2 = expf(a2 - m);
  const float inv = 1.0f / (e0 + e1 + e2);
  const float l0 = L[id];
  const float l1 = L[NROWS * NCLS + id];
  const float l2 = L[2 * NROWS * NCLS + id];
  const float s0 = 1.0f / (1.0f + expf(-l0));
  const float s1 = 1.0f / (1.0f + expf(-l1));
  const float s2 = 1.0f / (1.0f + expf(-l2));
  fused[id] = (e0 * s0 + e1 * s1 + e2 * s2) * inv;
}

__global__ __launch_bounds__(128) void head_kernel(const float* __restrict__ fused,
    const float* __restrict__ W1, const float* __restrict__ b1,
    const float* __restrict__ W2, const float* __restrict__ b2,
    float* __restrict__ out) {
  const int r = blockIdx.x, t = threadIdx.x;
  __shared__ float f[NCLS];
  __shared__ float hh[128];
  if (t < NCLS) f[t] = fused[r * NCLS + t];
  __syncthreads();
  float s = b1[t];
  #pragma unroll
  for (int k = 0; k < NCLS; ++k) s += f[k] * W1[k * 128 + t];
  hh[t] = s >= 0.f ? s : 0.25f * s;
  __syncthreads();
  if (t < NCLS) {
    float o = b2[t];
    for (int k = 0; k < 128; ++k) o += hh[k] * W2[k * NCLS + t];
    out[r * NCLS + t] = o;
  }
}

// ---------------------------------------------------------------------------
extern "C" void kernel_launch(void* const* d_in, const int* in_sizes, int n_in,
                              void* d_out, int out_size, void* d_ws, size_t ws_size,
                              hipStream_t stream) {
  const float* x0 = (const float*)d_in[0];
  const float* x1 = (const float*)d_in[1];
  const float* x2 = (const float*)d_in[2];
  const float* eW0 = (const float*)d_in[3];
  const float* eW1 = (const float*)d_in[4];
  const float* eW2 = (const float*)d_in[5];
  const float* enc_b = (const float*)d_in[6];
  const float* bn_g  = (const float*)d_in[7];
  const float* bn_b  = (const float*)d_in[8];
  const float* gc1W  = (const float*)d_in[9];
  const float* gc1b  = (const float*)d_in[10];
  const float* gc2W  = (const float*)d_in[11];
  const float* gc2b  = (const float*)d_in[12];
  const float* clfW  = (const float*)d_in[13];
  const float* clfb  = (const float*)d_in[14];
  const float* attn  = (const float*)d_in[15];
  const float* f1W   = (const float*)d_in[16];
  const float* f1b   = (const float*)d_in[17];
  const float* f2W   = (const float*)d_in[18];
  const float* f2b   = (const float*)d_in[19];
  float* out = (float*)d_out;

  int Kp[3];
  for (int m = 0; m < 3; ++m) {
    const int D = in_sizes[m] / NROWS;
    int k = 256;
    while (k < D) k <<= 1;
    Kp[m] = k;
  }
  const size_t KpSum = (size_t)Kp[0] + Kp[1] + Kp[2];
  const int D0 = in_sizes[0] / NROWS, D1 = in_sizes[1] / NROWS, D2 = in_sizes[2] / NROWS;

  // ---- Workspace layout with lifetime unions (~151 MB total) ----
  const size_t NH = (size_t)NROWS * HID;   // 2M elems
  float* ws = (float*)d_ws;
  // U1: A (encoder out, dead after bn_rownorm) aliases C (gc gemm temp)
  float* A = ws;                                    // 3*NH
  float* C = A;                                     // alias
  float* nval = A + 3 * NH;
  int*   nidx = (int*)(nval + (size_t)3 * NROWS * TOPK);
  float* dinv = (float*)(nidx + (size_t)3 * NROWS * TOPK);
  float* logits = dinv + 3 * NROWS;
  float* fused = logits + (size_t)3 * NROWS * NCLS;
  float* ps    = fused + (size_t)NROWS * NCLS;
  float* ps2   = ps + 3 * 64 * HID;
  float* scale = ps2 + 3 * 64 * HID;
  float* shift = scale + 3 * HID;
  float* M     = shift + 3 * HID;                   // 3*NROWS*64
  float* tauv  = M + (size_t)3 * NROWS * 64;
  int*   gcnt  = (int*)(tauv + 3 * NROWS);
  // U2: gidx (dead after refine) aliases Bf (gc2 output)
  int*   gidx  = gcnt + 3 * NROWS;                  // 3*NROWS*CAP
  float* Bf    = (float*)gidx;                      // alias
  ushort* WhG = (ushort*)(gidx + (size_t)3 * NROWS * CAP);  // 3*HID*HID
  ushort* WlG = WhG + (size_t)3 * HID * HID;
  ushort* WhE = WlG + (size_t)3 * HID * HID;        // HID*KpSum (compact)
  ushort* WlE = WhE + (size_t)HID * KpSum;
  // U3 (big union): enc A-limb planes (dead after enc gemm) overlay
  //                 FN + Ph + Fh + Fl + Hh + Hl
  char* u3 = (char*)(WlE + (size_t)HID * KpSum);
  float* FN = (float*)u3;                           // 3*NH fp32
  ushort* Ph = (ushort*)(FN + 3 * NH);              // 3*NH each below
  ushort* Fh = Ph + 3 * NH;
  ushort* Fl = Fh + 3 * NH;
  ushort* Hh = Fl + 3 * NH;
  ushort* Hl = Hh + 3 * NH;
  ushort* AhE = (ushort*)u3;                        // NROWS*KpSum (compact)
  ushort* AlE = AhE + (size_t)NROWS * KpSum;

  const size_t aOff0 = 0, aOff1 = (size_t)NROWS * Kp[0],
               aOff2 = (size_t)NROWS * (Kp[0] + Kp[1]);
  const size_t wOff0 = 0, wOff1 = (size_t)HID * Kp[0],
               wOff2 = (size_t)HID * (Kp[0] + Kp[1]);

  const dim3 blk(256);
  // Stage 1: encoder (batched over modalities)
  packAB_kernel<<<dim3(((NROWS + HID) * 1024) / 256, 3), blk, 0, stream>>>(
      x0, x1, x2, eW0, eW1, eW2, AhE, AlE, WhE, WlE,
      D0, D1, D2, Kp[0], Kp[1], Kp[2], aOff0, aOff1, aOff2, wOff0, wOff1, wOff2);
  limbgemm_kernel<true, 1><<<dim3(512, 3), blk, 0, stream>>>(
      AhE, AlE, WhE, WlE, enc_b, A, Kp[0], Kp[1], Kp[2],
      aOff0, aOff1, aOff2, wOff0, wOff1, wOff2);
  // Stage 2: BN + rownorm + limb emit (AhE/AlE dead; FN..Fl live in U3)
  bn_stats_kernel<<<dim3(64, 3), blk, 0, stream>>>(A, ps, ps2);
  bn_finalize_kernel<<<3, blk, 0, stream>>>(ps, ps2, bn_g, bn_b, scale, shift);
  bn_rownorm_kernel<<<dim3(NROWS, 3), blk, 0, stream>>>(A, scale, shift, FN, Ph, Fh, Fl);
  // Stage 3: symmetric stripe-free knn graph
  simtile_kernel<0><<<dim3(64, 64, 3), dim3(512), 0, stream>>>(Ph, M, nullptr, nullptr, nullptr);
  tau_kernel<<<dim3(NROWS / 4, 3), blk, 0, stream>>>(M, tauv, gcnt);
  simtile_kernel<1><<<dim3(64, 64, 3), dim3(512), 0, stream>>>(Ph, nullptr, tauv, gcnt, gidx);
  refine_kernel<<<dim3(NROWS / 4, 3), blk, 0, stream>>>(gcnt, gidx, FN, nidx, nval, dinv);
  // Stage 4: gc1 (A dead -> C reuses U1)
  packW_kernel<<<dim3(256, 3), blk, 0, stream>>>(gc1W, WhG, WlG);
  limbgemm_kernel<false, 0><<<dim3(512, 3), blk, 0, stream>>>(
      Fh, Fl, WhG, WlG, nullptr, C, HID, HID, HID,
      0, NH, 2 * NH, 0, (size_t)HID * HID, (size_t)2 * HID * HID);
  spmm_kernel<1><<<dim3(NROWS, 3), blk, 0, stream>>>(C, nidx, nval, dinv, gc1b,
                                                     nullptr, Hh, Hl);
  // Stage 5: gc2 (gidx dead -> Bf reuses U2)
  packW_kernel<<<dim3(256, 3), blk, 0, stream>>>(gc2W, WhG, WlG);
  limbgemm_kernel<false, 0><<<dim3(512, 3), blk, 0, stream>>>(
      Hh, Hl, WhG, WlG, nullptr, C, HID, HID, HID,
      0, NH, 2 * NH, 0, (size_t)HID * HID, (size_t)2 * HID * HID);
  spmm_kernel<0><<<dim3(NROWS, 3), blk, 0, stream>>>(C, nidx, nval, dinv, gc2b,
                                                     Bf, nullptr, nullptr);
  // Stage 6: classifier + fusion head
  clf_kernel<<<dim3((NROWS * NCLS + 255) / 256, 3), blk, 0, stream>>>(Bf, clfW, clfb, logits);
  fuse_kernel<<<(NROWS * NCLS + 255) / 256, blk, 0, stream>>>(logits, attn, fused);
  head_kernel<<<NROWS, dim3(128), 0, stream>>>(fused, f1W, f1b, f2W, f2b, out);
}

// Round 15
// 810.210 us; speedup vs baseline: 1.7847x; 1.0355x over previous
//
#include <hip/hip_runtime.h>
#include <cfloat>
#include <cstdint>
#include <cstddef>

#define NROWS 8192
#define HID 256
#define NCLS 5
#define TOPK 10
#define CAP 256     // per-row candidate capacity (typ. ~20-60 used)
#define TM 128
#define TN 128
#define BK 32
#define BKS 64      // sim K-step

typedef __bf16 bf16x8 __attribute__((ext_vector_type(8)));
typedef float f32x4 __attribute__((ext_vector_type(4)));

__device__ inline ushort f2bf(float x) {
  unsigned u = __float_as_uint(x);
  unsigned r = (u + 0x7fffu + ((u >> 16) & 1u)) >> 16;  // RNE
  return (ushort)r;
}
__device__ inline float bf2f(ushort b) { return __uint_as_float(((unsigned)b) << 16); }

// async global->LDS 16B/lane; LDS dest is wave-uniform base + lane*16
__device__ __forceinline__ void load_lds16(const void* g, void* l) {
  __builtin_amdgcn_global_load_lds(
      (const __attribute__((address_space(1))) void*)g,
      (__attribute__((address_space(3))) void*)l, 16, 0, 0);
}

// ---------------------------------------------------------------------------
// Batched encoder pack (z = modality): X -> hi/lo limb planes (COMPACT per-z
// row stride Kp[z], zero-padded past D), W -> transposed [HID x Kp[z]] planes.
// ---------------------------------------------------------------------------
__global__ __launch_bounds__(256) void packAB_kernel(const float* __restrict__ X0,
    const float* __restrict__ X1, const float* __restrict__ X2,
    const float* __restrict__ W0, const float* __restrict__ W1,
    const float* __restrict__ W2, ushort* __restrict__ Ah, ushort* __restrict__ Al,
    ushort* __restrict__ Bh, ushort* __restrict__ Bl,
    int D0, int D1, int D2, int Kp0, int Kp1, int Kp2,
    size_t aOff0, size_t aOff1, size_t aOff2,
    size_t wOff0, size_t wOff1, size_t wOff2) {
  const int z = blockIdx.y;
  const float* X = (z == 0) ? X0 : (z == 1) ? X1 : X2;
  const float* W = (z == 0) ? W0 : (z == 1) ? W1 : W2;
  const int D = (z == 0) ? D0 : (z == 1) ? D1 : D2;
  const int Kp = (z == 0) ? Kp0 : (z == 1) ? Kp1 : Kp2;
  const size_t aOff = (z == 0) ? aOff0 : (z == 1) ? aOff1 : aOff2;
  const size_t wOff = (z == 0) ? wOff0 : (z == 1) ? wOff1 : wOff2;
  const int ksh = 31 - __clz(Kp);
  const int id = blockIdx.x * 256 + threadIdx.x;
  const int atotal = NROWS << ksh;
  if (id >= atotal + (HID << ksh)) return;
  if (id < atotal) {
    const int k = id & (Kp - 1);
    const int r = id >> ksh;
    const float x = (k < D) ? X[(size_t)r * D + k] : 0.f;
    const ushort h = f2bf(x);
    Ah[aOff + id] = h;
    Al[aOff + id] = f2bf(x - bf2f(h));
  } else {
    const int id2 = id - atotal;
    const int k = id2 & (Kp - 1);
    const int n = id2 >> ksh;
    const float x = (k < D) ? W[(size_t)k * HID + n] : 0.f;
    const ushort h = f2bf(x);
    Bh[wOff + id2] = h;
    Bl[wOff + id2] = f2bf(x - bf2f(h));
  }
}

// ---------------------------------------------------------------------------
// Batched GCN weight pack: W[z] [HID x HID] -> transposed limb planes.
// ---------------------------------------------------------------------------
__global__ __launch_bounds__(256) void packW_kernel(const float* __restrict__ W,
    ushort* __restrict__ Bh, ushort* __restrict__ Bl) {
  const int z = blockIdx.y;
  const int id = blockIdx.x * 256 + threadIdx.x;  // 65536 per z
  const int k = id >> 8, n = id & 255;
  const size_t wz = (size_t)z * HID * HID;
  const float x = W[wz + (size_t)k * HID + n];
  const ushort h = f2bf(x);
  Bh[wz + (size_t)n * HID + k] = h;
  Bl[wz + (size_t)n * HID + k] = f2bf(x - bf2f(h));
}

// ---------------------------------------------------------------------------
// Batched 3-segment two-limb bf16 MFMA GEMM, 128x128 tile (2 col-blocks ->
// A limb planes fetched 2x from HBM instead of 4x). 4 waves (2x2), wave =
// 64x64 = acc[4][4]. Staging/fragment swizzle identical to the proven
// simgemm mapping (TM=128, BK=32). Per-k accumulation order (hh,hl,lh)
// unchanged -> bit-identical to the 64x64 version.
// ---------------------------------------------------------------------------
template<bool BIAS, int ACT>
__global__ __launch_bounds__(256) void limbgemm_kernel(const ushort* __restrict__ Ah,
    const ushort* __restrict__ Al, const ushort* __restrict__ Bh,
    const ushort* __restrict__ Bl, const float* __restrict__ bias,
    float* __restrict__ C, int Kp0, int Kp1, int Kp2,
    size_t aOff0, size_t aOff1, size_t aOff2,
    size_t bOff0, size_t bOff1, size_t bOff2) {
  __shared__ ushort AsH[TM * BK], AsL[TM * BK], BsH[TM * BK], BsL[TM * BK];
  const int z = blockIdx.y;
  const int Kp = (z == 0) ? Kp0 : (z == 1) ? Kp1 : Kp2;
  const size_t aO = (z == 0) ? aOff0 : (z == 1) ? aOff1 : aOff2;
  const size_t bO = (z == 0) ? bOff0 : (z == 1) ? bOff1 : bOff2;
  Ah += aO; Al += aO; Bh += bO; Bl += bO;
  C += (size_t)z * NROWS * HID;
  const int tid = threadIdx.x;
  const int wave = tid >> 6, lane = tid & 63;
  // XCD swizzle: 128 blocks = 64 row-blocks x 2 col-blocks
  const int bid = blockIdx.x;
  const int xcd = bid & 7, slot = bid >> 3;      // slot 0..15
  const int bxi = slot & 1;
  const int byi = xcd * 8 + (slot >> 1);
  const int bm = byi * TM, bn = bxi * 128;
  const int wr = (wave >> 1) * 64, wc = (wave & 1) * 64;

  f32x4 acc[4][4];
  const f32x4 zero = {0.f, 0.f, 0.f, 0.f};
  #pragma unroll
  for (int i = 0; i < 4; ++i)
    #pragma unroll
    for (int j = 0; j < 4; ++j) acc[i][j] = zero;

  // staging slots (proven R4 mapping): p in {tid, tid+256}, r=p>>2,
  // kl = (p&3) ^ ((r&3) ^ ((r>>2)&1))
  const int p0 = tid, p1 = tid + 256;
  const int r0 = p0 >> 2, kl0 = (p0 & 3) ^ ((r0 & 3) ^ ((r0 >> 2) & 1));
  const int r1 = p1 >> 2, kl1 = (p1 & 3) ^ ((r1 & 3) ^ ((r1 >> 2) & 1));
  const size_t a0 = (size_t)(bm + r0) * Kp + kl0 * 8;
  const size_t a1 = (size_t)(bm + r1) * Kp + kl1 * 8;
  const size_t b0 = (size_t)(bn + r0) * Kp + kl0 * 8;
  const size_t b1 = (size_t)(bn + r1) * Kp + kl1 * 8;

  for (int k0 = 0; k0 < Kp; k0 += BK) {
    __syncthreads();
    load_lds16(Ah + a0 + k0, &AsH[p0 * 8]);
    load_lds16(Ah + a1 + k0, &AsH[p1 * 8]);
    load_lds16(Al + a0 + k0, &AsL[p0 * 8]);
    load_lds16(Al + a1 + k0, &AsL[p1 * 8]);
    load_lds16(Bh + b0 + k0, &BsH[p0 * 8]);
    load_lds16(Bh + b1 + k0, &BsH[p1 * 8]);
    load_lds16(Bl + b0 + k0, &BsL[p0 * 8]);
    load_lds16(Bl + b1 + k0, &BsL[p1 * 8]);
    __syncthreads();
    bf16x8 ah[4], al[4], bh[4], bl[4];
    const int kg = lane >> 4;
    #pragma unroll
    for (int f = 0; f < 4; ++f) {
      const int m = wr + f * 16 + (lane & 15);
      const int sa = m * 4 + (kg ^ (m & 3) ^ ((m >> 2) & 1));
      ah[f] = *(const bf16x8*)&AsH[sa * 8];
      al[f] = *(const bf16x8*)&AsL[sa * 8];
      const int n = wc + f * 16 + (lane & 15);
      const int sb = n * 4 + (kg ^ (n & 3) ^ ((n >> 2) & 1));
      bh[f] = *(const bf16x8*)&BsH[sb * 8];
      bl[f] = *(const bf16x8*)&BsL[sb * 8];
    }
    #pragma unroll
    for (int fr = 0; fr < 4; ++fr)
      #pragma unroll
      for (int fc = 0; fc < 4; ++fc) {
        acc[fr][fc] = __builtin_amdgcn_mfma_f32_16x16x32_bf16(ah[fr], bh[fc], acc[fr][fc], 0, 0, 0);
        acc[fr][fc] = __builtin_amdgcn_mfma_f32_16x16x32_bf16(ah[fr], bl[fc], acc[fr][fc], 0, 0, 0);
        acc[fr][fc] = __builtin_amdgcn_mfma_f32_16x16x32_bf16(al[fr], bh[fc], acc[fr][fc], 0, 0, 0);
      }
  }
  const int cq = lane >> 4, cc = lane & 15;
  #pragma unroll
  for (int fr = 0; fr < 4; ++fr) {
    #pragma unroll
    for (int fc = 0; fc < 4; ++fc) {
      const int rb = bm + wr + fr * 16 + cq * 4;
      const int col = bn + wc + fc * 16 + cc;
      const float bb = BIAS ? bias[z * HID + col] : 0.f;
      float* cp = C + (size_t)rb * HID + col;
      #pragma unroll
      for (int e = 0; e < 4; ++e) {
        float v = acc[fr][fc][e] + bb;
        if (ACT == 1) v = fmaxf(v, 0.f);
        cp[(size_t)e * HID] = v;
      }
    }
  }
}

// ---------------------------------------------------------------------------
// Batched coalesced BatchNorm, 3 stages.
// ---------------------------------------------------------------------------
__global__ __launch_bounds__(256) void bn_stats_kernel(const float* __restrict__ F,
    float* __restrict__ ps, float* __restrict__ ps2) {
  const int z = blockIdx.y;
  const int b = blockIdx.x, t = threadIdx.x;
  float s = 0.f, s2 = 0.f;
  const float* p = F + (size_t)z * NROWS * HID + (size_t)b * 128 * HID + t;
  for (int r = 0; r < 128; ++r) {
    const float v = p[(size_t)r * HID];
    s += v; s2 += v * v;
  }
  ps[(size_t)z * 64 * HID + b * HID + t] = s;
  ps2[(size_t)z * 64 * HID + b * HID + t] = s2;
}

__global__ __launch_bounds__(256) void bn_finalize_kernel(const float* __restrict__ ps,
    const float* __restrict__ ps2, const float* __restrict__ g,
    const float* __restrict__ b, float* __restrict__ scale, float* __restrict__ shift) {
  const int z = blockIdx.x;
  const int t = threadIdx.x;
  float s = 0.f, s2 = 0.f;
  for (int i = 0; i < 64; ++i) {
    s += ps[(size_t)z * 64 * HID + i * HID + t];
    s2 += ps2[(size_t)z * 64 * HID + i * HID + t];
  }
  const float mu = s / (float)NROWS;
  const float var = s2 / (float)NROWS - mu * mu;
  const float rstd = rsqrtf(var + 1e-5f);
  const float sc = rstd * g[z * HID + t];
  scale[z * HID + t] = sc;
  shift[z * HID + t] = b[z * HID + t] - mu * sc;
}

// ---------------------------------------------------------------------------
// Batched fused bn-apply + L2 rownorm. Emits FN, Ph (hi-limb fn), Fh/Fl.
// ---------------------------------------------------------------------------
__global__ __launch_bounds__(256) void bn_rownorm_kernel(const float* __restrict__ F,
    const float* __restrict__ scale, const float* __restrict__ shift,
    float* __restrict__ FN, ushort* __restrict__ Ph,
    ushort* __restrict__ Fh, ushort* __restrict__ Fl) {
  const int z = blockIdx.y;
  const int r = blockIdx.x, t = threadIdx.x;
  const size_t zb = (size_t)z * NROWS * HID;
  const float f = F[zb + (size_t)r * HID + t] * scale[z * HID + t] + shift[z * HID + t];
  __shared__ float sh[256];
  sh[t] = f * f;
  __syncthreads();
  for (int st = 128; st > 0; st >>= 1) {
    if (t < st) sh[t] += sh[t + st];
    __syncthreads();
  }
  const float inv = 1.0f / fmaxf(sqrtf(sh[0]), 1e-12f);
  const float fn = f * inv;
  const size_t o = zb + (size_t)r * HID + t;
  FN[o] = fn;
  Ph[o] = f2bf(fn);
  const ushort h = f2bf(f);
  Fh[o] = h;
  Fl[o] = f2bf(f - bf2f(h));
}

// ---------------------------------------------------------------------------
// Batched SYMMETRIC stripe-free sim (z = blockIdx.z): upper-triangle tile
// pairs only; off-diag tiles serve row band AND column band from registers.
// PASS 0: per-row/per-col tile maxes -> M. PASS 1: tau-compaction both dirs.
// ---------------------------------------------------------------------------
template<int PASS>
__global__ __launch_bounds__(512) void simtile_kernel(const ushort* __restrict__ P,
    float* __restrict__ M, const float* __restrict__ tauv,
    int* __restrict__ gcnt, int* __restrict__ gidx) {
  const int bx = blockIdx.x, by = blockIdx.y;
  if (by > bx) return;
  const int z = blockIdx.z;
  P += (size_t)z * NROWS * HID;
  if (PASS == 0) M += (size_t)z * NROWS * 64;
  else {
    tauv += (size_t)z * NROWS;
    gcnt += (size_t)z * NROWS;
    gidx += (size_t)z * NROWS * CAP;
  }
  const bool offdiag = (bx != by);
  __shared__ ushort As[TM * BKS];
  __shared__ ushort Bs[TN * BKS];
  __shared__ float Ml[2][TM];
  __shared__ float MlC[4][TN];
  __shared__ float taulA[TM];
  __shared__ float taulB[TN];
  const int tid = threadIdx.x;
  const int wave = tid >> 6, lane = tid & 63;
  const int bm = by * TM;
  const int bn = bx * TN;
  const int wr = (wave >> 1) * 32;
  const int wc = (wave & 1) * 64;

  if (PASS == 1) {
    if (tid < TM) taulA[tid] = tauv[bm + tid];
    else if (tid < TM + TN) taulB[tid - TM] = tauv[bn + (tid - TM)];
  }

  const ushort* pa[2];
  const ushort* pb[2];
  #pragma unroll
  for (int j = 0; j < 2; ++j) {
    const int s = tid + j * 512;
    const int m = s >> 3;
    const int kg = (s & 7) ^ (m & 7);
    pa[j] = P + (size_t)(bm + m) * HID + kg * 8;
    pb[j] = P + (size_t)(bn + m) * HID + kg * 8;
  }

  f32x4 acc[2][4];
  const f32x4 zero = {0.f, 0.f, 0.f, 0.f};
  #pragma unroll
  for (int i = 0; i < 2; ++i)
    #pragma unroll
    for (int j = 0; j < 4; ++j) acc[i][j] = zero;

  for (int k0 = 0; k0 < HID; k0 += BKS) {
    __syncthreads();
    #pragma unroll
    for (int j = 0; j < 2; ++j) {
      load_lds16(pa[j] + k0, &As[(tid + j * 512) * 8]);
      load_lds16(pb[j] + k0, &Bs[(tid + j * 512) * 8]);
    }
    __syncthreads();
    #pragma unroll
    for (int h = 0; h < 2; ++h) {
      const int kgb = h * 4 + (lane >> 4);
      bf16x8 af[2], bf[4];
      #pragma unroll
      for (int f = 0; f < 2; ++f) {
        const int m = wr + f * 16 + (lane & 15);
        const int sa = m * 8 + (kgb ^ (m & 7));
        af[f] = *(const bf16x8*)&As[sa * 8];
      }
      #pragma unroll
      for (int f = 0; f < 4; ++f) {
        const int n = wc + f * 16 + (lane & 15);
        const int sb = n * 8 + (kgb ^ (n & 7));
        bf[f] = *(const bf16x8*)&Bs[sb * 8];
      }
      #pragma unroll
      for (int fr = 0; fr < 2; ++fr)
        #pragma unroll
        for (int fc = 0; fc < 4; ++fc)
          acc[fr][fc] = __builtin_amdgcn_mfma_f32_16x16x32_bf16(af[fr], bf[fc], acc[fr][fc], 0, 0, 0);
    }
  }

  const int cq = lane >> 4, cc = lane & 15;
  if (PASS == 0) {
    #pragma unroll
    for (int fr = 0; fr < 2; ++fr) {
      #pragma unroll
      for (int e = 0; e < 4; ++e) {
        const int lrow = wr + fr * 16 + cq * 4 + e;
        const int grow = bm + lrow;
        float mx = -FLT_MAX;
        #pragma unroll
        for (int fc = 0; fc < 4; ++fc) {
          const int col = bn + wc + fc * 16 + cc;
          mx = fmaxf(mx, (col == grow) ? -FLT_MAX : acc[fr][fc][e]);
        }
        #pragma unroll
        for (int s = 1; s < 16; s <<= 1) mx = fmaxf(mx, __shfl_xor(mx, s));
        if (cc == 0) Ml[wave & 1][lrow] = mx;
      }
    }
    if (offdiag) {
      #pragma unroll
      for (int fc = 0; fc < 4; ++fc) {
        float mx = -FLT_MAX;
        #pragma unroll
        for (int fr = 0; fr < 2; ++fr)
          #pragma unroll
          for (int e = 0; e < 4; ++e) mx = fmaxf(mx, acc[fr][fc][e]);
        mx = fmaxf(mx, __shfl_xor(mx, 16));
        mx = fmaxf(mx, __shfl_xor(mx, 32));
        if (cq == 0) MlC[wave >> 1][wc + fc * 16 + cc] = mx;
      }
    }
    __syncthreads();
    if (tid < TM) M[(size_t)(bm + tid) * 64 + bx] = fmaxf(Ml[0][tid], Ml[1][tid]);
    if (offdiag && tid < TN) {
      const float mx = fmaxf(fmaxf(MlC[0][tid], MlC[1][tid]),
                             fmaxf(MlC[2][tid], MlC[3][tid]));
      M[(size_t)(bn + tid) * 64 + by] = mx;
    }
  } else {
    __syncthreads();
    #pragma unroll
    for (int fr = 0; fr < 2; ++fr) {
      #pragma unroll
      for (int e = 0; e < 4; ++e) {
        const int lrow = wr + fr * 16 + cq * 4 + e;
        const int grow = bm + lrow;
        const float tA = taulA[lrow];
        #pragma unroll
        for (int fc = 0; fc < 4; ++fc) {
          const int lcol = wc + fc * 16 + cc;
          const int gcol = bn + lcol;
          const float v = acc[fr][fc][e];
          if (gcol != grow && v >= tA) {
            const int pos = atomicAdd(&gcnt[grow], 1);
            if (pos < CAP) gidx[(size_t)grow * CAP + pos] = gcol;
          }
          if (offdiag && v >= taulB[lcol]) {
            const int pos = atomicAdd(&gcnt[gcol], 1);
            if (pos < CAP) gidx[(size_t)gcol * CAP + pos] = grow;
          }
        }
      }
    }
  }
}

// ---------------------------------------------------------------------------
// Batched tau: tau[row] = 16th largest of 64 tile-maxes; zeroes gcnt.
// ---------------------------------------------------------------------------
__global__ __launch_bounds__(256) void tau_kernel(const float* __restrict__ M,
    float* __restrict__ tauv, int* __restrict__ gcnt) {
  const int z = blockIdx.y;
  const int wave = threadIdx.x >> 6, lane = threadIdx.x & 63;
  const int row = blockIdx.x * 4 + wave;
  float cur = M[(size_t)z * NROWS * 64 + (size_t)row * 64 + lane];
  float tau = cur;
  #pragma unroll
  for (int sel = 0; sel < 16; ++sel) {
    float bv = cur;
    int bl = lane;
    #pragma unroll
    for (int s = 1; s < 64; s <<= 1) {
      const float ov = __shfl_xor(bv, s);
      const int ol = __shfl_xor(bl, s);
      if (ov > bv || (ov == bv && ol < bl)) { bv = ov; bl = ol; }
    }
    tau = bv;
    if (lane == bl) cur = -FLT_MAX;
  }
  if (lane == 0) {
    tauv[(size_t)z * NROWS + row] = tau;
    gcnt[(size_t)z * NROWS + row] = 0;
  }
}

// ---------------------------------------------------------------------------
// Batched exact refinement: fp32 dots for all candidates, exact top-10.
// ---------------------------------------------------------------------------
__global__ __launch_bounds__(256) void refine_kernel(const int* __restrict__ gcnt,
    const int* __restrict__ gidx, const float* __restrict__ FN,
    int* __restrict__ nidx, float* __restrict__ nval, float* __restrict__ dinv) {
  const int z = blockIdx.y;
  gcnt += (size_t)z * NROWS;
  gidx += (size_t)z * NROWS * CAP;
  FN += (size_t)z * NROWS * HID;
  nidx += (size_t)z * NROWS * TOPK;
  nval += (size_t)z * NROWS * TOPK;
  dinv += (size_t)z * NROWS;
  const int wave = threadIdx.x >> 6, lane = threadIdx.x & 63;
  const int row = blockIdx.x * 4 + wave;
  const int cnt = min(gcnt[row], CAP);
  __shared__ float fnrow[4][HID];
  __shared__ float ev[4][CAP];
  ((float4*)fnrow[wave])[lane] = ((const float4*)(FN + (size_t)row * HID))[lane];
  __syncthreads();
  const int c = lane >> 2, q4 = lane & 3;
  for (int b0 = 0; b0 < cnt; b0 += 16) {
    const int ci = b0 + c;
    const int cand = (ci < cnt) ? gidx[(size_t)row * CAP + ci] : 0;
    float s = 0.f;
    const float* fc = FN + (size_t)cand * HID + q4 * 64;
    const float* fr = fnrow[wave] + q4 * 64;
    #pragma unroll 8
    for (int k = 0; k < 64; ++k) s += fr[k] * fc[k];
    s += __shfl_xor(s, 1);
    s += __shfl_xor(s, 2);
    if (q4 == 0 && ci < cnt) ev[wave][ci] = s;
  }
  __syncthreads();
  float outv[TOPK];
  int outi[TOPK];
  float sum = 1.0f;  // diag contributes 1
  #pragma unroll
  for (int sel = 0; sel < TOPK; ++sel) {
    float bv = -FLT_MAX;
    int bp = 0;
    #pragma unroll
    for (int j = 0; j < 4; ++j) {
      const int p = lane + j * 64;
      if (p < cnt) {
        const float v = ev[wave][p];
        if (v > bv) { bv = v; bp = p; }
      }
    }
    #pragma unroll
    for (int s = 1; s < 64; s <<= 1) {
      const float ov = __shfl_xor(bv, s);
      const int op = __shfl_xor(bp, s);
      if (ov > bv || (ov == bv && op < bp)) { bv = ov; bp = op; }
    }
    outv[sel] = bv;
    outi[sel] = bp;
    sum += fabsf(bv);
    if (lane == 0) ev[wave][bp] = -FLT_MAX;
  }
  if (lane == 0) {
    const float inv = 1.0f / fmaxf(sum, 1e-12f);
    dinv[row] = inv;
    #pragma unroll
    for (int sel = 0; sel < TOPK; ++sel) {
      nval[row * TOPK + sel] = outv[sel] * inv;
      nidx[row * TOPK + sel] = gidx[(size_t)row * CAP + outi[sel]];
    }
  }
}

// ---------------------------------------------------------------------------
// Batched sparse adj (11 nnz/row) @ T + bias, leaky_relu(0.25).
// EMIT=1: write two-limb bf16 planes (gc2's A side).
// EMIT=0: fused classifier epilogue — the h2 row lives in this block's
//         registers; 5 wave-shuffle reductions produce logits directly
//         (h2 never round-trips HBM).
// ---------------------------------------------------------------------------
template<int EMIT>
__global__ __launch_bounds__(256) void spmm_kernel(const float* __restrict__ T,
    const int* __restrict__ nidx, const float* __restrict__ nval,
    const float* __restrict__ dinv, const float* __restrict__ bias,
    ushort* __restrict__ Hh, ushort* __restrict__ Hl,
    const float* __restrict__ clfW, const float* __restrict__ clfb,
    float* __restrict__ L) {
  const int z = blockIdx.y;
  const size_t zb = (size_t)z * NROWS * HID;
  T += zb;
  nidx += (size_t)z * NROWS * TOPK;
  nval += (size_t)z * NROWS * TOPK;
  dinv += (size_t)z * NROWS;
  const int r = blockIdx.x, c = threadIdx.x;
  float acc = dinv[r] * T[(size_t)r * HID + c];
  #pragma unroll
  for (int n = 0; n < TOPK; ++n) {
    acc += nval[r * TOPK + n] * T[(size_t)nidx[r * TOPK + n] * HID + c];
  }
  acc += bias[z * HID + c];
  const float v = acc >= 0.f ? acc : 0.25f * acc;
  if (EMIT == 1) {
    const size_t o = zb + (size_t)r * HID + c;
    const ushort h = f2bf(v);
    Hh[o] = h;
    Hl[o] = f2bf(v - bf2f(h));
  } else {
    // fused classifier: logits[r][cls] = sum_c v[c] * W[c][cls] + b[cls]
    __shared__ float wsum[4][NCLS];
    const int wave = c >> 6, lane = c & 63;
    const float* wrow = clfW + (size_t)z * HID * NCLS + (size_t)c * NCLS;
    #pragma unroll
    for (int cls = 0; cls < NCLS; ++cls) {
      float p = v * wrow[cls];
      #pragma unroll
      for (int s = 1; s < 64; s <<= 1) p += __shfl_xor(p, s);
      if (lane == 0) wsum[wave][cls] = p;
    }
    __syncthreads();
    if (c < NCLS) {
      const float lg = clfb[z * NCLS + c] + wsum[0][c] + wsum[1][c] + wsum[2][c] + wsum[3][c];
      L[(size_t)z * NROWS * NCLS + (size_t)r * NCLS + c] = lg;
    }
  }
}

__global__ __launch_bounds__(256) void fuse_kernel(const float* __restrict__ L,
    const float* __restrict__ attn, float* __restrict__ fused) {
  const int id = blockIdx.x * 256 + threadIdx.x;
  if (id >= NROWS * NCLS) return;
  const float a0 = attn[0], a1 = attn[1], a2 = attn[2];
  const float m = fmaxf(a0, fmaxf(a1, a2));
  const float e0 = expf(a0 - m), e1 = expf(a1 - m), e2 = expf(a2 - m);
  const float inv = 1.0f / (e0 + e1 + e2);
  const float l0 = L[id];
  const float l1 = L[NROWS * NCLS + id];
  const float l2 = L[2 * NROWS * NCLS + id];
  const float s0 = 1.0f / (1.0f + expf(-l0));
  const float s1 = 1.0f / (1.0f + expf(-l1));
  const float s2 = 1.0f / (1.0f + expf(-l2));
  fused[id] = (e0 * s0 + e1 * s1 + e2 * s2) * inv;
}

__global__ __launch_bounds__(128) void head_kernel(const float* __restrict__ fused,
    const float* __restrict__ W1, const float* __restrict__ b1,
    const float* __restrict__ W2, const float* __restrict__ b2,
    float* __restrict__ out) {
  const int r = blockIdx.x, t = threadIdx.x;
  __shared__ float f[NCLS];
  __shared__ float hh[128];
  if (t < NCLS) f[t] = fused[r * NCLS + t];
  __syncthreads();
  float s = b1[t];
  #pragma unroll
  for (int k = 0; k < NCLS; ++k) s += f[k] * W1[k * 128 + t];
  hh[t] = s >= 0.f ? s : 0.25f * s;
  __syncthreads();
  if (t < NCLS) {
    float o = b2[t];
    for (int k = 0; k < 128; ++k) o += hh[k] * W2[k * NCLS + t];
    out[r * NCLS + t] = o;
  }
}

// ---------------------------------------------------------------------------
extern "C" void kernel_launch(void* const* d_in, const int* in_sizes, int n_in,
                              void* d_out, int out_size, void* d_ws, size_t ws_size,
                              hipStream_t stream) {
  const float* x0 = (const float*)d_in[0];
  const float* x1 = (const float*)d_in[1];
  const float* x2 = (const float*)d_in[2];
  const float* eW0 = (const float*)d_in[3];
  const float* eW1 = (const float*)d_in[4];
  const float* eW2 = (const float*)d_in[5];
  const float* enc_b = (const float*)d_in[6];
  const float* bn_g  = (const float*)d_in[7];
  const float* bn_b  = (const float*)d_in[8];
  const float* gc1W  = (const float*)d_in[9];
  const float* gc1b  = (const float*)d_in[10];
  const float* gc2W  = (const float*)d_in[11];
  const float* gc2b  = (const float*)d_in[12];
  const float* clfW  = (const float*)d_in[13];
  const float* clfb  = (const float*)d_in[14];
  const float* attn  = (const float*)d_in[15];
  const float* f1W   = (const float*)d_in[16];
  const float* f1b   = (const float*)d_in[17];
  const float* f2W   = (const float*)d_in[18];
  const float* f2b   = (const float*)d_in[19];
  float* out = (float*)d_out;

  int Kp[3];
  for (int m = 0; m < 3; ++m) {
    const int D = in_sizes[m] / NROWS;
    int k = 256;
    while (k < D) k <<= 1;
    Kp[m] = k;
  }
  const size_t KpSum = (size_t)Kp[0] + Kp[1] + Kp[2];
  const int D0 = in_sizes[0] / NROWS, D1 = in_sizes[1] / NROWS, D2 = in_sizes[2] / NROWS;

  // ---- Workspace layout with lifetime unions (~151 MB total) ----
  const size_t NH = (size_t)NROWS * HID;   // 2M elems
  float* ws = (float*)d_ws;
  // U1: A (encoder out, dead after bn_rownorm) aliases C (gc gemm temp)
  float* A = ws;                                    // 3*NH
  float* C = A;                                     // alias
  float* nval = A + 3 * NH;
  int*   nidx = (int*)(nval + (size_t)3 * NROWS * TOPK);
  float* dinv = (float*)(nidx + (size_t)3 * NROWS * TOPK);
  float* logits = dinv + 3 * NROWS;
  float* fused = logits + (size_t)3 * NROWS * NCLS;
  float* ps    = fused + (size_t)NROWS * NCLS;
  float* ps2   = ps + 3 * 64 * HID;
  float* scale = ps2 + 3 * 64 * HID;
  float* shift = scale + 3 * HID;
  float* M     = shift + 3 * HID;                   // 3*NROWS*64
  float* tauv  = M + (size_t)3 * NROWS * 64;
  int*   gcnt  = (int*)(tauv + 3 * NROWS);
  int*   gidx  = gcnt + 3 * NROWS;                  // 3*NROWS*CAP
  ushort* WhG = (ushort*)(gidx + (size_t)3 * NROWS * CAP);  // 3*HID*HID
  ushort* WlG = WhG + (size_t)3 * HID * HID;
  ushort* WhE = WlG + (size_t)3 * HID * HID;        // HID*KpSum (compact)
  ushort* WlE = WhE + (size_t)HID * KpSum;
  // U3 (big union): enc A-limb planes (dead after enc gemm) overlay
  //                 FN + Ph + Fh + Fl + Hh + Hl
  char* u3 = (char*)(WlE + (size_t)HID * KpSum);
  float* FN = (float*)u3;                           // 3*NH fp32
  ushort* Ph = (ushort*)(FN + 3 * NH);              // 3*NH each below
  ushort* Fh = Ph + 3 * NH;
  ushort* Fl = Fh + 3 * NH;
  ushort* Hh = Fl + 3 * NH;
  ushort* Hl = Hh + 3 * NH;
  ushort* AhE = (ushort*)u3;                        // NROWS*KpSum (compact)
  ushort* AlE = AhE + (size_t)NROWS * KpSum;

  const size_t aOff0 = 0, aOff1 = (size_t)NROWS * Kp[0],
               aOff2 = (size_t)NROWS * (Kp[0] + Kp[1]);
  const size_t wOff0 = 0, wOff1 = (size_t)HID * Kp[0],
               wOff2 = (size_t)HID * (Kp[0] + Kp[1]);

  const dim3 blk(256);
  // Stage 1: encoder (batched over modalities)
  packAB_kernel<<<dim3(((NROWS + HID) * 1024) / 256, 3), blk, 0, stream>>>(
      x0, x1, x2, eW0, eW1, eW2, AhE, AlE, WhE, WlE,
      D0, D1, D2, Kp[0], Kp[1], Kp[2], aOff0, aOff1, aOff2, wOff0, wOff1, wOff2);
  limbgemm_kernel<true, 1><<<dim3(128, 3), blk, 0, stream>>>(
      AhE, AlE, WhE, WlE, enc_b, A, Kp[0], Kp[1], Kp[2],
      aOff0, aOff1, aOff2, wOff0, wOff1, wOff2);
  // Stage 2: BN + rownorm + limb emit (AhE/AlE dead; FN..Fl live in U3)
  bn_stats_kernel<<<dim3(64, 3), blk, 0, stream>>>(A, ps, ps2);
  bn_finalize_kernel<<<3, blk, 0, stream>>>(ps, ps2, bn_g, bn_b, scale, shift);
  bn_rownorm_kernel<<<dim3(NROWS, 3), blk, 0, stream>>>(A, scale, shift, FN, Ph, Fh, Fl);
  // Stage 3: symmetric stripe-free knn graph
  simtile_kernel<0><<<dim3(64, 64, 3), dim3(512), 0, stream>>>(Ph, M, nullptr, nullptr, nullptr);
  tau_kernel<<<dim3(NROWS / 4, 3), blk, 0, stream>>>(M, tauv, gcnt);
  simtile_kernel<1><<<dim3(64, 64, 3), dim3(512), 0, stream>>>(Ph, nullptr, tauv, gcnt, gidx);
  refine_kernel<<<dim3(NROWS / 4, 3), blk, 0, stream>>>(gcnt, gidx, FN, nidx, nval, dinv);
  // Stage 4: gc1 (A dead -> C reuses U1)
  packW_kernel<<<dim3(256, 3), blk, 0, stream>>>(gc1W, WhG, WlG);
  limbgemm_kernel<false, 0><<<dim3(128, 3), blk, 0, stream>>>(
      Fh, Fl, WhG, WlG, nullptr, C, HID, HID, HID,
      0, NH, 2 * NH, 0, (size_t)HID * HID, (size_t)2 * HID * HID);
  spmm_kernel<1><<<dim3(NROWS, 3), blk, 0, stream>>>(C, nidx, nval, dinv, gc1b,
                                                     Hh, Hl, nullptr, nullptr, nullptr);
  // Stage 5: gc2 + fused classifier (h2 never hits HBM)
  packW_kernel<<<dim3(256, 3), blk, 0, stream>>>(gc2W, WhG, WlG);
  limbgemm_kernel<false, 0><<<dim3(128, 3), blk, 0, stream>>>(
      Hh, Hl, WhG, WlG, nullptr, C, HID, HID, HID,
      0, NH, 2 * NH, 0, (size_t)HID * HID, (size_t)2 * HID * HID);
  spmm_kernel<0><<<dim3(NROWS, 3), blk, 0, stream>>>(C, nidx, nval, dinv, gc2b,
                                                     nullptr, nullptr, clfW, clfb, logits);
  // Stage 6: fusion head
  fuse_kernel<<<(NROWS * NCLS + 255) / 256, blk, 0, stream>>>(logits, attn, fused);
  head_kernel<<<NROWS, dim3(128), 0, stream>>>(fused, f1W, f1b, f2W, f2b, out);
}